// Round 3
// baseline (275.947 us; speedup 1.0000x reference)
//
#include <hip/hip_runtime.h>
#include <math.h>

#define HIDDEN 128
#define NSTEP  64
#define BATCH2 4096
#define OUTD   100
#define E      16
#define LDA    136   // shorts per Abuf row (272 B; stride 68 dwords -> bank-uniform for b64/b128)

typedef __attribute__((ext_vector_type(8))) short  short8;
typedef __attribute__((ext_vector_type(4))) float  f32x4;

// pack two f32 -> two bf16 (round-to-nearest, ties up) in 3 VALU ops
static __device__ __forceinline__ unsigned pack2(float f0, float f1) {
    unsigned u0 = __float_as_uint(f0) + 0x8000u;
    unsigned u1 = __float_as_uint(f1) + 0x8000u;
    return __builtin_amdgcn_perm(u1, u0, 0x07060302u); // bytes {u0.b2,u0.b3,u1.b2,u1.b3}
}
static __device__ __forceinline__ float fast_tanh(float z) {
    float e = __expf(2.0f * z);
    return 1.0f - 2.0f / (e + 1.0f);
}

// One setup kernel: bf16-transpose W2/W3 into d_ws, zero u accumulator, write u0.
__global__ __launch_bounds__(256) void setup_kernel(
    const float* __restrict__ W2, const float* __restrict__ W3,
    const float* __restrict__ samples_s,
    short* __restrict__ wbf, float* __restrict__ out)
{
    int t = blockIdx.x * blockDim.x + threadIdx.x;   // 0..32767
    int m = t >> 14, r = t & 16383, n = r >> 7, k = r & 127;
    const float* W = m ? W3 : W2;
    unsigned u = __float_as_uint(W[k * HIDDEN + n]) + 0x8000u;
    wbf[t] = (short)(u >> 16);
    if (t < BATCH2) {
        out[t] = 0.0f;
        float s0 = samples_s[t * (NSTEP + 1)];
        out[BATCH2 + t] = 3.9894228040143267f * expf(-500000.0f * s0 * s0);
    }
}

__global__ __launch_bounds__(256) void eval_kernel(
    const float* __restrict__ W1, const float* __restrict__ b1,
    const float* __restrict__ b2, const float* __restrict__ b3,
    const float* __restrict__ W4, const float* __restrict__ b4,
    const short* __restrict__ wbf,
    const int*   __restrict__ samples_n,
    const float* __restrict__ samples_s,
    const float* __restrict__ samples_dB,
    const float* __restrict__ tptr,
    float* __restrict__ out)
{
    // Activations, [buf][tangent][eval][h] bf16, double-buffered across layers
    __shared__ short Abuf[2][3][E][LDA];
    __shared__ float sContrib[E];

    const int tid = threadIdx.x;
    const float t  = tptr[0];
    const float dt = t / (float)NSTEP;
    const int b  = blockIdx.x >> 2;          // sample (4 blocks per sample)
    const int j0 = (blockIdx.x & 3) * 16;

    const int e   = tid >> 4;                // eval owned in layer1/layer4 roles
    const int sub = tid & 15;
    const int j   = j0 + e;
    const int c   = NSTEP - j;

    // ---- layer 1: elementwise, thread covers (e, h0..h0+7) ----
    {
        float s  = samples_s[b * (NSTEP + 1) + c];
        float tk = (j == 0) ? t : t - dt * (float)(j - 1);
        int h0 = sub * 8;
        float wa[8], wb[8], bv[8];
        *(float4*)&wa[0] = ((const float4*)W1)[sub * 2];
        *(float4*)&wa[4] = ((const float4*)W1)[sub * 2 + 1];
        *(float4*)&wb[0] = ((const float4*)(W1 + HIDDEN))[sub * 2];
        *(float4*)&wb[4] = ((const float4*)(W1 + HIDDEN))[sub * 2 + 1];
        *(float4*)&bv[0] = ((const float4*)b1)[sub * 2];
        *(float4*)&bv[4] = ((const float4*)b1)[sub * 2 + 1];
        float av[8], d1[8], d2[8];
        #pragma unroll
        for (int i = 0; i < 8; ++i) {
            float z = fmaf(wa[i], s, fmaf(wb[i], tk, bv[i]));
            float a = fast_tanh(z);
            float g = 1.0f - a * a;
            float ad = g * wa[i];              // z' = wa, z'' = 0
            float add = -2.0f * a * ad * wa[i];
            av[i] = a; d1[i] = ad; d2[i] = add;
        }
        uint4 p0 = { pack2(av[0],av[1]), pack2(av[2],av[3]), pack2(av[4],av[5]), pack2(av[6],av[7]) };
        uint4 p1 = { pack2(d1[0],d1[1]), pack2(d1[2],d1[3]), pack2(d1[4],d1[5]), pack2(d1[6],d1[7]) };
        uint4 p2 = { pack2(d2[0],d2[1]), pack2(d2[2],d2[3]), pack2(d2[4],d2[5]), pack2(d2[6],d2[7]) };
        *(uint4*)&Abuf[0][0][e][h0] = p0;
        *(uint4*)&Abuf[0][1][e][h0] = p1;
        *(uint4*)&Abuf[0][2][e][h0] = p2;
    }

    const int lane = tid & 63;
    const int wv   = tid >> 6;               // wave owns h-tiles 2wv, 2wv+1
    const int quad = lane >> 4;
    const int m16  = lane & 15;

    // ---- layers 2, 3: Z^T = W^T * Act^T via MFMA (A = weights, B = activations) ----
    int bufIn = 0;
    #pragma unroll
    for (int layer = 0; layer < 2; ++layer) {
        __syncthreads();
        const short* __restrict__ WTl  = wbf + layer * (HIDDEN * HIDDEN);
        const float* __restrict__ bias = layer ? b3 : b2;

        f32x4 acc[2][3];
        #pragma unroll
        for (int mt = 0; mt < 2; ++mt)
            #pragma unroll
            for (int tp = 0; tp < 3; ++tp)
                acc[mt][tp] = (f32x4){0.f, 0.f, 0.f, 0.f};

        #pragma unroll
        for (int kk = 0; kk < 4; ++kk) {
            const int k0 = kk * 32 + quad * 8;
            short8 bfrag[3];
            #pragma unroll
            for (int tp = 0; tp < 3; ++tp)
                bfrag[tp] = *(const short8*)&Abuf[bufIn][tp][m16][k0];
            short8 afrag[2];
            #pragma unroll
            for (int mt = 0; mt < 2; ++mt) {
                int m = (wv * 2 + mt) * 16 + m16;
                afrag[mt] = *(const short8*)&WTl[m * HIDDEN + k0];
            }
            #pragma unroll
            for (int mt = 0; mt < 2; ++mt)
                #pragma unroll
                for (int tp = 0; tp < 3; ++tp)
                    acc[mt][tp] = __builtin_amdgcn_mfma_f32_16x16x32_bf16(
                        afrag[mt], bfrag[tp], acc[mt][tp], 0, 0, 0);
        }

        // epilogue: lane holds eval=m16, rows h0..h0+3 -> tanh chain, pack, b64 writes
        const int bufOut = bufIn ^ 1;
        #pragma unroll
        for (int mt = 0; mt < 2; ++mt) {
            int h0 = (wv * 2 + mt) * 16 + quad * 4;
            float bias4[4];
            *(float4*)&bias4[0] = *(const float4*)(bias + h0);
            float a[4], d1[4], d2[4];
            #pragma unroll
            for (int r = 0; r < 4; ++r) {
                float zv  = acc[mt][0][r] + bias4[r];
                float zd  = acc[mt][1][r];
                float zdd = acc[mt][2][r];
                float av = fast_tanh(zv);
                float g  = 1.0f - av * av;
                float ad = g * zd;
                float add = fmaf(g, zdd, -2.0f * av * ad * zd);
                a[r] = av; d1[r] = ad; d2[r] = add;
            }
            uint2 w0 = { pack2(a[0],  a[1]),  pack2(a[2],  a[3])  };
            uint2 w1 = { pack2(d1[0], d1[1]), pack2(d1[2], d1[3]) };
            uint2 w2 = { pack2(d2[0], d2[1]), pack2(d2[2], d2[3]) };
            *(uint2*)&Abuf[bufOut][0][m16][h0] = w0;
            *(uint2*)&Abuf[bufOut][1][m16][h0] = w1;
            *(uint2*)&Abuf[bufOut][2][m16][h0] = w2;
        }
        bufIn ^= 1;
    }
    __syncthreads();

    // ---- layer 4: dot over h with W4[:, n_e]; 16 lanes per eval, 8 h each ----
    {
        int n = samples_n[b * (NSTEP + 1) + c];
        uint4 uv = *(const uint4*)&Abuf[0][0][e][sub * 8];
        uint4 ud = *(const uint4*)&Abuf[0][1][e][sub * 8];
        uint4 u2 = *(const uint4*)&Abuf[0][2][e][sub * 8];
        const float* W4p = W4 + (sub * 8) * OUTD + n;
        float sv = 0.f, sd = 0.f, sdd = 0.f;
        unsigned uvv[4] = {uv.x, uv.y, uv.z, uv.w};
        unsigned udv[4] = {ud.x, ud.y, ud.z, ud.w};
        unsigned u2v[4] = {u2.x, u2.y, u2.z, u2.w};
        #pragma unroll
        for (int i = 0; i < 4; ++i) {
            float wlo = W4p[(2 * i) * OUTD];
            float whi = W4p[(2 * i + 1) * OUTD];
            sv  = fmaf(__uint_as_float(uvv[i] << 16),          wlo, sv);
            sv  = fmaf(__uint_as_float(uvv[i] & 0xffff0000u),  whi, sv);
            sd  = fmaf(__uint_as_float(udv[i] << 16),          wlo, sd);
            sd  = fmaf(__uint_as_float(udv[i] & 0xffff0000u),  whi, sd);
            sdd = fmaf(__uint_as_float(u2v[i] << 16),          wlo, sdd);
            sdd = fmaf(__uint_as_float(u2v[i] & 0xffff0000u),  whi, sdd);
        }
        #pragma unroll
        for (int off = 8; off >= 1; off >>= 1) {
            sv  += __shfl_xor(sv,  off, 16);
            sd  += __shfl_xor(sd,  off, 16);
            sdd += __shfl_xor(sdd, off, 16);
        }
        if (sub == 0) {
            float u  = sv + b4[n];
            float dB = samples_dB[b * NSTEP + (NSTEP - 1 - j)];
            float contrib = -(sd * dB + sdd * dt * 0.5f);
            if (j == 0) contrib += u;
            sContrib[e] = contrib;
        }
    }
    __syncthreads();

    if (tid == 0) {
        float tot = 0.f;
        #pragma unroll
        for (int k = 0; k < E; ++k) tot += sContrib[k];
        atomicAdd(&out[b], tot);
    }
}

extern "C" void kernel_launch(void* const* d_in, const int* in_sizes, int n_in,
                              void* d_out, int out_size, void* d_ws, size_t ws_size,
                              hipStream_t stream) {
    const float* W1 = (const float*)d_in[0];
    const float* b1 = (const float*)d_in[1];
    const float* W2 = (const float*)d_in[2];
    const float* b2 = (const float*)d_in[3];
    const float* W3 = (const float*)d_in[4];
    const float* b3 = (const float*)d_in[5];
    const float* W4 = (const float*)d_in[6];
    const float* b4 = (const float*)d_in[7];
    const int*   sn  = (const int*)d_in[8];
    const float* ss  = (const float*)d_in[9];
    const float* sdB = (const float*)d_in[10];
    const float* t   = (const float*)d_in[11];
    float* out = (float*)d_out;
    short* wbf = (short*)d_ws;   // 64 KB: W2^T, W3^T in bf16

    setup_kernel<<<(2 * HIDDEN * HIDDEN) / 256, 256, 0, stream>>>(W2, W3, ss, wbf, out);
    eval_kernel<<<(BATCH2 * NSTEP) / E, 256, 0, stream>>>(
        W1, b1, b2, b3, W4, b4, wbf, sn, ss, sdB, t, out);
}

// Round 4
// 232.333 us; speedup vs baseline: 1.1877x; 1.1877x over previous
//
#include <hip/hip_runtime.h>
#include <math.h>

#define HIDDEN 128
#define NSTEP  64
#define BATCH2 4096
#define OUTD   100
#define E      32    // evals per block (half a sample)
#define LDA    136   // shorts per Abuf row (272 B, 16B-aligned rows)

typedef __attribute__((ext_vector_type(8))) short  short8;
typedef __attribute__((ext_vector_type(4))) float  f32x4;

// pack two f32 -> two bf16 (round-to-nearest, ties up) in 3 VALU ops
static __device__ __forceinline__ unsigned pack2(float f0, float f1) {
    unsigned u0 = __float_as_uint(f0) + 0x8000u;
    unsigned u1 = __float_as_uint(f1) + 0x8000u;
    return __builtin_amdgcn_perm(u1, u0, 0x07060302u);
}
static __device__ __forceinline__ float fast_tanh(float z) {
    float e = __expf(2.0f * z);
    return 1.0f - 2.0f / (e + 1.0f);
}

// Setup: bf16-transpose W2/W3 into d_ws, zero u accumulator, write u0.
__global__ __launch_bounds__(256) void setup_kernel(
    const float* __restrict__ W2, const float* __restrict__ W3,
    const float* __restrict__ samples_s,
    short* __restrict__ wbf, float* __restrict__ out)
{
    int t = blockIdx.x * blockDim.x + threadIdx.x;   // 0..32767
    int m = t >> 14, r = t & 16383, n = r >> 7, k = r & 127;
    const float* W = m ? W3 : W2;
    unsigned u = __float_as_uint(W[k * HIDDEN + n]) + 0x8000u;
    wbf[t] = (short)(u >> 16);
    if (t < BATCH2) {
        out[t] = 0.0f;
        float s0 = samples_s[t * (NSTEP + 1)];
        out[BATCH2 + t] = 3.9894228040143267f * expf(-500000.0f * s0 * s0);
    }
}

__global__ __launch_bounds__(256) void eval_kernel(
    const float* __restrict__ W1, const float* __restrict__ b1,
    const float* __restrict__ b2, const float* __restrict__ b3,
    const float* __restrict__ W4, const float* __restrict__ b4,
    const short* __restrict__ wbf,
    const int*   __restrict__ samples_n,
    const float* __restrict__ samples_s,
    const float* __restrict__ samples_dB,
    const float* __restrict__ tptr,
    float* __restrict__ out)
{
    __shared__ short Abuf[3][E][LDA];   // [tangent][eval][h] bf16, single buffer
    __shared__ float sContrib[E];

    const int tid = threadIdx.x;
    const float t  = tptr[0];
    const float dt = t / (float)NSTEP;
    const int b  = blockIdx.x >> 1;          // sample (2 blocks per sample)
    const int j0 = (blockIdx.x & 1) * E;

    const int sub  = tid & 15;
    const int egrp = tid >> 4;               // 0..15

    // ---- layer 1: thread covers evals {egrp, egrp+16} x h[sub*8 .. sub*8+7] ----
    {
        const int h0 = sub * 8;
        float wa[8], wb[8], bv[8];
        *(float4*)&wa[0] = ((const float4*)W1)[sub * 2];
        *(float4*)&wa[4] = ((const float4*)W1)[sub * 2 + 1];
        *(float4*)&wb[0] = ((const float4*)(W1 + HIDDEN))[sub * 2];
        *(float4*)&wb[4] = ((const float4*)(W1 + HIDDEN))[sub * 2 + 1];
        *(float4*)&bv[0] = ((const float4*)b1)[sub * 2];
        *(float4*)&bv[4] = ((const float4*)b1)[sub * 2 + 1];
        #pragma unroll
        for (int it = 0; it < 2; ++it) {
            const int e = egrp + it * 16;
            const int j = j0 + e;
            const int c = NSTEP - j;
            float s  = samples_s[b * (NSTEP + 1) + c];
            float tk = (j == 0) ? t : t - dt * (float)(j - 1);
            float av[8], d1[8], d2[8];
            #pragma unroll
            for (int i = 0; i < 8; ++i) {
                float z = fmaf(wa[i], s, fmaf(wb[i], tk, bv[i]));
                float a = fast_tanh(z);
                float g = 1.0f - a * a;
                float ad = g * wa[i];              // z' = wa, z'' = 0
                float add = -2.0f * a * ad * wa[i];
                av[i] = a; d1[i] = ad; d2[i] = add;
            }
            uint4 p0 = { pack2(av[0],av[1]), pack2(av[2],av[3]), pack2(av[4],av[5]), pack2(av[6],av[7]) };
            uint4 p1 = { pack2(d1[0],d1[1]), pack2(d1[2],d1[3]), pack2(d1[4],d1[5]), pack2(d1[6],d1[7]) };
            uint4 p2 = { pack2(d2[0],d2[1]), pack2(d2[2],d2[3]), pack2(d2[4],d2[5]), pack2(d2[6],d2[7]) };
            *(uint4*)&Abuf[0][e][h0] = p0;
            *(uint4*)&Abuf[1][e][h0] = p1;
            *(uint4*)&Abuf[2][e][h0] = p2;
        }
    }

    const int lane = tid & 63;
    const int wv   = tid >> 6;               // wave owns h-tiles 2wv, 2wv+1
    const int quad = lane >> 4;
    const int m16  = lane & 15;

    // ---- layers 2, 3: Z^T = W^T * Act^T; A = weights (2 M-tiles), B = acts (2 N-tiles) ----
    #pragma unroll
    for (int layer = 0; layer < 2; ++layer) {
        __syncthreads();
        const short* __restrict__ WTl  = wbf + layer * (HIDDEN * HIDDEN);
        const float* __restrict__ bias = layer ? b3 : b2;

        f32x4 acc[2][2][3];   // [mt][nt][tangent]
        #pragma unroll
        for (int mt = 0; mt < 2; ++mt)
            #pragma unroll
            for (int nt = 0; nt < 2; ++nt)
                #pragma unroll
                for (int tp = 0; tp < 3; ++tp)
                    acc[mt][nt][tp] = (f32x4){0.f, 0.f, 0.f, 0.f};

        #pragma unroll
        for (int kk = 0; kk < 4; ++kk) {
            const int k0 = kk * 32 + quad * 8;
            short8 afrag[2];
            #pragma unroll
            for (int mt = 0; mt < 2; ++mt) {
                int m = (wv * 2 + mt) * 16 + m16;
                afrag[mt] = *(const short8*)&WTl[m * HIDDEN + k0];
            }
            #pragma unroll
            for (int tp = 0; tp < 3; ++tp) {
                short8 bf0 = *(const short8*)&Abuf[tp][m16][k0];
                short8 bf1 = *(const short8*)&Abuf[tp][16 + m16][k0];
                #pragma unroll
                for (int mt = 0; mt < 2; ++mt) {
                    acc[mt][0][tp] = __builtin_amdgcn_mfma_f32_16x16x32_bf16(
                        afrag[mt], bf0, acc[mt][0][tp], 0, 0, 0);
                    acc[mt][1][tp] = __builtin_amdgcn_mfma_f32_16x16x32_bf16(
                        afrag[mt], bf1, acc[mt][1][tp], 0, 0, 0);
                }
            }
        }

        // epilogue: lane holds (eval = nt*16+m16, h = tile + quad*4 + r)
        uint2 wout[2][2][3];
        #pragma unroll
        for (int mt = 0; mt < 2; ++mt) {
            int h0 = (wv * 2 + mt) * 16 + quad * 4;
            float bias4[4];
            *(float4*)&bias4[0] = *(const float4*)(bias + h0);
            #pragma unroll
            for (int nt = 0; nt < 2; ++nt) {
                float a[4], d1[4], d2[4];
                #pragma unroll
                for (int r = 0; r < 4; ++r) {
                    float zv  = acc[mt][nt][0][r] + bias4[r];
                    float zd  = acc[mt][nt][1][r];
                    float zdd = acc[mt][nt][2][r];
                    float av = fast_tanh(zv);
                    float g  = 1.0f - av * av;
                    float ad = g * zd;
                    float add = fmaf(g, zdd, -2.0f * av * ad * zd);
                    a[r] = av; d1[r] = ad; d2[r] = add;
                }
                wout[mt][nt][0] = (uint2){ pack2(a[0],  a[1]),  pack2(a[2],  a[3])  };
                wout[mt][nt][1] = (uint2){ pack2(d1[0], d1[1]), pack2(d1[2], d1[3]) };
                wout[mt][nt][2] = (uint2){ pack2(d2[0], d2[1]), pack2(d2[2], d2[3]) };
            }
        }
        __syncthreads();   // all Abuf reads done before overwrite
        #pragma unroll
        for (int mt = 0; mt < 2; ++mt) {
            int h0 = (wv * 2 + mt) * 16 + quad * 4;
            #pragma unroll
            for (int nt = 0; nt < 2; ++nt) {
                int e = nt * 16 + m16;
                *(uint2*)&Abuf[0][e][h0] = wout[mt][nt][0];
                *(uint2*)&Abuf[1][e][h0] = wout[mt][nt][1];
                *(uint2*)&Abuf[2][e][h0] = wout[mt][nt][2];
            }
        }
    }
    __syncthreads();

    // ---- layer 4: dot over h with W4[:, n_e]; 16 lanes per eval, 2 evals/thread ----
    #pragma unroll
    for (int it = 0; it < 2; ++it) {
        const int e = egrp + it * 16;
        const int j = j0 + e;
        const int c = NSTEP - j;
        int n = samples_n[b * (NSTEP + 1) + c];
        uint4 uv = *(const uint4*)&Abuf[0][e][sub * 8];
        uint4 ud = *(const uint4*)&Abuf[1][e][sub * 8];
        uint4 u2 = *(const uint4*)&Abuf[2][e][sub * 8];
        const float* W4p = W4 + (sub * 8) * OUTD + n;
        float sv = 0.f, sd = 0.f, sdd = 0.f;
        unsigned uvv[4] = {uv.x, uv.y, uv.z, uv.w};
        unsigned udv[4] = {ud.x, ud.y, ud.z, ud.w};
        unsigned u2v[4] = {u2.x, u2.y, u2.z, u2.w};
        #pragma unroll
        for (int i = 0; i < 4; ++i) {
            float wlo = W4p[(2 * i) * OUTD];
            float whi = W4p[(2 * i + 1) * OUTD];
            sv  = fmaf(__uint_as_float(uvv[i] << 16),          wlo, sv);
            sv  = fmaf(__uint_as_float(uvv[i] & 0xffff0000u),  whi, sv);
            sd  = fmaf(__uint_as_float(udv[i] << 16),          wlo, sd);
            sd  = fmaf(__uint_as_float(udv[i] & 0xffff0000u),  whi, sd);
            sdd = fmaf(__uint_as_float(u2v[i] << 16),          wlo, sdd);
            sdd = fmaf(__uint_as_float(u2v[i] & 0xffff0000u),  whi, sdd);
        }
        #pragma unroll
        for (int off = 8; off >= 1; off >>= 1) {
            sv  += __shfl_xor(sv,  off, 16);
            sd  += __shfl_xor(sd,  off, 16);
            sdd += __shfl_xor(sdd, off, 16);
        }
        if (sub == 0) {
            float u  = sv + b4[n];
            float dB = samples_dB[b * NSTEP + (NSTEP - 1 - j)];
            float contrib = -(sd * dB + sdd * dt * 0.5f);
            if (j == 0) contrib += u;
            sContrib[e] = contrib;
        }
    }
    __syncthreads();

    // block-level reduce of 32 contribs -> one atomic
    if (tid < 64) {
        float v = (tid < E) ? sContrib[tid] : 0.0f;
        #pragma unroll
        for (int off = 16; off >= 1; off >>= 1)
            v += __shfl_xor(v, off, 32);
        if (tid == 0) atomicAdd(&out[b], v);
    }
}

extern "C" void kernel_launch(void* const* d_in, const int* in_sizes, int n_in,
                              void* d_out, int out_size, void* d_ws, size_t ws_size,
                              hipStream_t stream) {
    const float* W1 = (const float*)d_in[0];
    const float* b1 = (const float*)d_in[1];
    const float* W2 = (const float*)d_in[2];
    const float* b2 = (const float*)d_in[3];
    const float* W3 = (const float*)d_in[4];
    const float* b3 = (const float*)d_in[5];
    const float* W4 = (const float*)d_in[6];
    const float* b4 = (const float*)d_in[7];
    const int*   sn  = (const int*)d_in[8];
    const float* ss  = (const float*)d_in[9];
    const float* sdB = (const float*)d_in[10];
    const float* t   = (const float*)d_in[11];
    float* out = (float*)d_out;
    short* wbf = (short*)d_ws;   // 64 KB: W2^T, W3^T in bf16

    setup_kernel<<<(2 * HIDDEN * HIDDEN) / 256, 256, 0, stream>>>(W2, W3, ss, wbf, out);
    eval_kernel<<<(BATCH2 * NSTEP) / E, 256, 0, stream>>>(
        W1, b1, b2, b3, W4, b4, wbf, sn, ss, sdB, t, out);
}

// Round 5
// 203.858 us; speedup vs baseline: 1.3536x; 1.1397x over previous
//
#include <hip/hip_runtime.h>
#include <math.h>

#define HIDDEN 128
#define NSTEP  64
#define BATCH2 4096
#define OUTD   100
#define E      32    // evals per block (half a sample)
#define LDA    136   // shorts per Abuf row (272 B; 17-granule stride -> near-uniform banks)

typedef __attribute__((ext_vector_type(8))) short  short8;
typedef __attribute__((ext_vector_type(4))) float  f32x4;

// pack two f32 -> two bf16 (round-to-nearest, ties up) in 3 VALU ops
static __device__ __forceinline__ unsigned pack2(float f0, float f1) {
    unsigned u0 = __float_as_uint(f0) + 0x8000u;
    unsigned u1 = __float_as_uint(f1) + 0x8000u;
    return __builtin_amdgcn_perm(u1, u0, 0x07060302u);
}
static __device__ __forceinline__ float fast_tanh(float z) {
    float e = __expf(2.0f * z);
    return 1.0f - 2.0f / (e + 1.0f);
}

// Setup: bf16-transpose W2/W3 (wbf) and W4 (w4t) into d_ws; init out.
// d_ws layout (shorts): [0..32767] = W2T,W3T ; [32768..45567] = W4T[100][128]
__global__ __launch_bounds__(256) void setup_kernel(
    const float* __restrict__ W2, const float* __restrict__ W3,
    const float* __restrict__ W4,
    const float* __restrict__ samples_s,
    short* __restrict__ wbf, float* __restrict__ out)
{
    int t = blockIdx.x * blockDim.x + threadIdx.x;   // 0..32767
    int m = t >> 14, r = t & 16383, n = r >> 7, k = r & 127;
    const float* W = m ? W3 : W2;
    unsigned u = __float_as_uint(W[k * HIDDEN + n]) + 0x8000u;
    wbf[t] = (short)(u >> 16);
    if (t < OUTD * HIDDEN) {                         // W4T[n][h] = W4[h][n]
        int nn = t >> 7, h = t & 127;
        unsigned v = __float_as_uint(W4[h * OUTD + nn]) + 0x8000u;
        wbf[32768 + t] = (short)(v >> 16);
    }
    if (t < BATCH2) {
        out[t] = 0.0f;
        float s0 = samples_s[t * (NSTEP + 1)];
        out[BATCH2 + t] = 3.9894228040143267f * expf(-500000.0f * s0 * s0);
    }
}

__global__ __launch_bounds__(256) void eval_kernel(
    const float* __restrict__ W1, const float* __restrict__ b1,
    const float* __restrict__ b2, const float* __restrict__ b3,
    const float* __restrict__ b4,
    const short* __restrict__ wbf,
    const int*   __restrict__ samples_n,
    const float* __restrict__ samples_s,
    const float* __restrict__ samples_dB,
    const float* __restrict__ tptr,
    float* __restrict__ out)
{
    __shared__ short Abuf[3][E][LDA];   // [tangent][eval][h] bf16
    __shared__ float sContrib[E];

    const int tid = threadIdx.x;
    const float t  = tptr[0];
    const float dt = t / (float)NSTEP;
    const int b  = blockIdx.x >> 1;          // sample (2 blocks per sample)
    const int j0 = (blockIdx.x & 1) * E;

    const int sub  = tid & 15;
    const int egrp = tid >> 4;               // 0..15

    // ---- layer 1: thread covers evals {egrp, egrp+16} x h[sub*8 .. sub*8+7] ----
    {
        const int h0 = sub * 8;
        float wa[8], wb[8], bv[8];
        *(float4*)&wa[0] = ((const float4*)W1)[sub * 2];
        *(float4*)&wa[4] = ((const float4*)W1)[sub * 2 + 1];
        *(float4*)&wb[0] = ((const float4*)(W1 + HIDDEN))[sub * 2];
        *(float4*)&wb[4] = ((const float4*)(W1 + HIDDEN))[sub * 2 + 1];
        *(float4*)&bv[0] = ((const float4*)b1)[sub * 2];
        *(float4*)&bv[4] = ((const float4*)b1)[sub * 2 + 1];
        #pragma unroll
        for (int it = 0; it < 2; ++it) {
            const int e = egrp + it * 16;
            const int j = j0 + e;
            const int c = NSTEP - j;
            float s  = samples_s[b * (NSTEP + 1) + c];
            float tk = (j == 0) ? t : t - dt * (float)(j - 1);
            float av[8], d1[8], d2[8];
            #pragma unroll
            for (int i = 0; i < 8; ++i) {
                float z = fmaf(wa[i], s, fmaf(wb[i], tk, bv[i]));
                float a = fast_tanh(z);
                float g = 1.0f - a * a;
                float ad = g * wa[i];              // z' = wa, z'' = 0
                float add = -2.0f * a * ad * wa[i];
                av[i] = a; d1[i] = ad; d2[i] = add;
            }
            uint4 p0 = { pack2(av[0],av[1]), pack2(av[2],av[3]), pack2(av[4],av[5]), pack2(av[6],av[7]) };
            uint4 p1 = { pack2(d1[0],d1[1]), pack2(d1[2],d1[3]), pack2(d1[4],d1[5]), pack2(d1[6],d1[7]) };
            uint4 p2 = { pack2(d2[0],d2[1]), pack2(d2[2],d2[3]), pack2(d2[4],d2[5]), pack2(d2[6],d2[7]) };
            *(uint4*)&Abuf[0][e][h0] = p0;
            *(uint4*)&Abuf[1][e][h0] = p1;
            *(uint4*)&Abuf[2][e][h0] = p2;
        }
    }

    const int lane = tid & 63;
    const int wv   = tid >> 6;               // wave owns h-tiles 2wv, 2wv+1
    const int quad = lane >> 4;
    const int m16  = lane & 15;

    // ---- layers 2, 3: Z^T = W^T * Act^T; A = weights (2 M-tiles), B = acts (2 N-tiles) ----
    #pragma unroll
    for (int layer = 0; layer < 2; ++layer) {
        __syncthreads();
        const short* __restrict__ WTl  = wbf + layer * (HIDDEN * HIDDEN);
        const float* __restrict__ bias = layer ? b3 : b2;

        f32x4 acc[2][2][3];   // [mt][nt][tangent]
        #pragma unroll
        for (int mt = 0; mt < 2; ++mt)
            #pragma unroll
            for (int nt = 0; nt < 2; ++nt)
                #pragma unroll
                for (int tp = 0; tp < 3; ++tp)
                    acc[mt][nt][tp] = (f32x4){0.f, 0.f, 0.f, 0.f};

        #pragma unroll
        for (int kk = 0; kk < 4; ++kk) {
            const int k0 = kk * 32 + quad * 8;
            short8 afrag[2];
            #pragma unroll
            for (int mt = 0; mt < 2; ++mt) {
                int m = (wv * 2 + mt) * 16 + m16;
                afrag[mt] = *(const short8*)&WTl[m * HIDDEN + k0];
            }
            #pragma unroll
            for (int tp = 0; tp < 3; ++tp) {
                short8 bf0 = *(const short8*)&Abuf[tp][m16][k0];
                short8 bf1 = *(const short8*)&Abuf[tp][16 + m16][k0];
                #pragma unroll
                for (int mt = 0; mt < 2; ++mt) {
                    acc[mt][0][tp] = __builtin_amdgcn_mfma_f32_16x16x32_bf16(
                        afrag[mt], bf0, acc[mt][0][tp], 0, 0, 0);
                    acc[mt][1][tp] = __builtin_amdgcn_mfma_f32_16x16x32_bf16(
                        afrag[mt], bf1, acc[mt][1][tp], 0, 0, 0);
                }
            }
        }

        // epilogue: lane holds (eval = nt*16+m16, h = tile + quad*4 + r)
        uint2 wout[2][2][3];
        #pragma unroll
        for (int mt = 0; mt < 2; ++mt) {
            int h0 = (wv * 2 + mt) * 16 + quad * 4;
            float bias4[4];
            *(float4*)&bias4[0] = *(const float4*)(bias + h0);
            #pragma unroll
            for (int nt = 0; nt < 2; ++nt) {
                float a[4], d1[4], d2[4];
                #pragma unroll
                for (int r = 0; r < 4; ++r) {
                    float zv  = acc[mt][nt][0][r] + bias4[r];
                    float zd  = acc[mt][nt][1][r];
                    float zdd = acc[mt][nt][2][r];
                    float av = fast_tanh(zv);
                    float g  = 1.0f - av * av;
                    float ad = g * zd;
                    float add = fmaf(g, zdd, -2.0f * av * ad * zd);
                    a[r] = av; d1[r] = ad; d2[r] = add;
                }
                wout[mt][nt][0] = (uint2){ pack2(a[0],  a[1]),  pack2(a[2],  a[3])  };
                wout[mt][nt][1] = (uint2){ pack2(d1[0], d1[1]), pack2(d1[2], d1[3]) };
                wout[mt][nt][2] = (uint2){ pack2(d2[0], d2[1]), pack2(d2[2], d2[3]) };
            }
        }
        __syncthreads();   // all Abuf reads done before overwrite
        #pragma unroll
        for (int mt = 0; mt < 2; ++mt) {
            int h0 = (wv * 2 + mt) * 16 + quad * 4;
            #pragma unroll
            for (int nt = 0; nt < 2; ++nt) {
                int e = nt * 16 + m16;
                *(uint2*)&Abuf[0][e][h0] = wout[mt][nt][0];
                *(uint2*)&Abuf[1][e][h0] = wout[mt][nt][1];
                *(uint2*)&Abuf[2][e][h0] = wout[mt][nt][2];
            }
        }
    }
    __syncthreads();

    // ---- layer 4: coalesced bf16 W4T row reads; 16 lanes per eval, 2 evals/thread ----
    const short* __restrict__ w4t = wbf + 2 * HIDDEN * HIDDEN;
    #pragma unroll
    for (int it = 0; it < 2; ++it) {
        const int e = egrp + it * 16;
        const int j = j0 + e;
        const int c = NSTEP - j;
        int n = samples_n[b * (NSTEP + 1) + c];
        uint4 ud = *(const uint4*)&Abuf[1][e][sub * 8];
        uint4 u2 = *(const uint4*)&Abuf[2][e][sub * 8];
        uint4 w4 = *(const uint4*)&w4t[n * HIDDEN + sub * 8];   // coalesced 16B
        unsigned udv[4] = {ud.x, ud.y, ud.z, ud.w};
        unsigned u2v[4] = {u2.x, u2.y, u2.z, u2.w};
        unsigned w4v[4] = {w4.x, w4.y, w4.z, w4.w};
        float sd = 0.f, sdd = 0.f;
        #pragma unroll
        for (int i = 0; i < 4; ++i) {
            float wlo = __uint_as_float(w4v[i] << 16);
            float whi = __uint_as_float(w4v[i] & 0xffff0000u);
            sd  = fmaf(__uint_as_float(udv[i] << 16),          wlo, sd);
            sd  = fmaf(__uint_as_float(udv[i] & 0xffff0000u),  whi, sd);
            sdd = fmaf(__uint_as_float(u2v[i] << 16),          wlo, sdd);
            sdd = fmaf(__uint_as_float(u2v[i] & 0xffff0000u),  whi, sdd);
        }
        float sv = 0.f;
        if (j == 0) {       // value dot only needed at j==0 (uniform per 16-lane group)
            uint4 uv = *(const uint4*)&Abuf[0][e][sub * 8];
            unsigned uvv[4] = {uv.x, uv.y, uv.z, uv.w};
            #pragma unroll
            for (int i = 0; i < 4; ++i) {
                float wlo = __uint_as_float(w4v[i] << 16);
                float whi = __uint_as_float(w4v[i] & 0xffff0000u);
                sv = fmaf(__uint_as_float(uvv[i] << 16),         wlo, sv);
                sv = fmaf(__uint_as_float(uvv[i] & 0xffff0000u), whi, sv);
            }
        }
        #pragma unroll
        for (int off = 8; off >= 1; off >>= 1) {
            sd  += __shfl_xor(sd,  off, 16);
            sdd += __shfl_xor(sdd, off, 16);
            sv  += __shfl_xor(sv,  off, 16);
        }
        if (sub == 0) {
            float dB = samples_dB[b * NSTEP + (NSTEP - 1 - j)];
            float contrib = -(sd * dB + sdd * dt * 0.5f);
            if (j == 0) contrib += sv + b4[n];
            sContrib[e] = contrib;
        }
    }
    __syncthreads();

    // block-level reduce of 32 contribs -> one atomic
    if (tid < 64) {
        float v = (tid < E) ? sContrib[tid] : 0.0f;
        #pragma unroll
        for (int off = 16; off >= 1; off >>= 1)
            v += __shfl_xor(v, off, 32);
        if (tid == 0) atomicAdd(&out[b], v);
    }
}

extern "C" void kernel_launch(void* const* d_in, const int* in_sizes, int n_in,
                              void* d_out, int out_size, void* d_ws, size_t ws_size,
                              hipStream_t stream) {
    const float* W1 = (const float*)d_in[0];
    const float* b1 = (const float*)d_in[1];
    const float* W2 = (const float*)d_in[2];
    const float* b2 = (const float*)d_in[3];
    const float* W3 = (const float*)d_in[4];
    const float* b3 = (const float*)d_in[5];
    const float* W4 = (const float*)d_in[6];
    const float* b4 = (const float*)d_in[7];
    const int*   sn  = (const int*)d_in[8];
    const float* ss  = (const float*)d_in[9];
    const float* sdB = (const float*)d_in[10];
    const float* t   = (const float*)d_in[11];
    float* out = (float*)d_out;
    short* wbf = (short*)d_ws;   // 90 KB: W2^T, W3^T, W4^T in bf16

    setup_kernel<<<(2 * HIDDEN * HIDDEN) / 256, 256, 0, stream>>>(W2, W3, W4, ss, wbf, out);
    eval_kernel<<<(BATCH2 * NSTEP) / E, 256, 0, stream>>>(
        W1, b1, b2, b3, b4, wbf, sn, ss, sdB, t, out);
}

// Round 6
// 192.543 us; speedup vs baseline: 1.4332x; 1.0588x over previous
//
#include <hip/hip_runtime.h>
#include <math.h>

#define HIDDEN 128
#define NSTEP  64
#define BATCH2 4096
#define OUTD   100

typedef __attribute__((ext_vector_type(4))) short  short4v;
typedef __attribute__((ext_vector_type(8))) short  short8v;
typedef __attribute__((ext_vector_type(4))) float  f32x4;

// pack two f32 -> two bf16 (round-to-nearest, ties up); f0 in low short
static __device__ __forceinline__ unsigned pack2(float f0, float f1) {
    unsigned u0 = __float_as_uint(f0) + 0x8000u;
    unsigned u1 = __float_as_uint(f1) + 0x8000u;
    return __builtin_amdgcn_perm(u1, u0, 0x07060302u);
}
static __device__ __forceinline__ short4v pack4(float f0, float f1, float f2, float f3) {
    int2 p = { (int)pack2(f0, f1), (int)pack2(f2, f3) };
    return __builtin_bit_cast(short4v, p);
}
static __device__ __forceinline__ float fast_tanh(float z) {
    float e = __expf(2.0f * z);
    return 1.0f - 2.0f / (e + 1.0f);
}
static __device__ __forceinline__ f32x4 mfma16(short4v a, short4v b, f32x4 c) {
    return __builtin_amdgcn_mfma_f32_16x16x16bf16_1k(a, b, c, 0, 0, 0);
}

// Setup: bf16-transpose W2/W3 (wbf) and W4 (w4t) into d_ws; init out.
// d_ws layout (shorts): [0..32767] = W2T,W3T (WT[n][k]); [32768..45567] = W4T[100][128]
__global__ __launch_bounds__(256) void setup_kernel(
    const float* __restrict__ W2, const float* __restrict__ W3,
    const float* __restrict__ W4,
    const float* __restrict__ samples_s,
    short* __restrict__ wbf, float* __restrict__ out)
{
    int t = blockIdx.x * blockDim.x + threadIdx.x;   // 0..32767
    int m = t >> 14, r = t & 16383, n = r >> 7, k = r & 127;
    const float* W = m ? W3 : W2;
    unsigned u = __float_as_uint(W[k * HIDDEN + n]) + 0x8000u;
    wbf[t] = (short)(u >> 16);
    if (t < OUTD * HIDDEN) {                         // W4T[n][h] = W4[h][n]
        int nn = t >> 7, h = t & 127;
        unsigned v = __float_as_uint(W4[h * OUTD + nn]) + 0x8000u;
        wbf[32768 + t] = (short)(v >> 16);
    }
    if (t < BATCH2) {
        out[t] = 0.0f;
        float s0 = samples_s[t * (NSTEP + 1)];
        out[BATCH2 + t] = 3.9894228040143267f * expf(-500000.0f * s0 * s0);
    }
}

// One block = one sample = 64 evals. Wave w owns evals j = 16w + (lane&15),
// lane quad q holds k-slice {16kt + 4q + i}. Activations live entirely in
// registers (K16 MFMA C-frag == next layer's B-frag). One barrier total.
__global__ __launch_bounds__(256) void eval_kernel(
    const float* __restrict__ W1, const float* __restrict__ b1,
    const float* __restrict__ b2, const float* __restrict__ b3,
    const float* __restrict__ b4,
    const short* __restrict__ wbf,
    const int*   __restrict__ samples_n,
    const float* __restrict__ samples_s,
    const float* __restrict__ samples_dB,
    const float* __restrict__ tptr,
    float* __restrict__ out)
{
    // Weights, permuted: LDS[row*128 + ((q*32 + kt*4 + i + 8*(row&15)) & 127)]
    //  = WT[row&127][16kt + 4q + i]   (row = layer*128 + h_out)
    __shared__ short ldsW[2 * HIDDEN * HIDDEN];   // 64 KB

    const int tid  = threadIdx.x;
    const int w    = tid >> 6;
    const int lane = tid & 63;
    const int m16  = lane & 15;
    const int q    = lane >> 4;
    const int b    = blockIdx.x;

    // ---- stage weights (coalesced read, permuted+rotated write) ----
    {
        const int k0 = 2 * lane;
        const int pBase = ((k0 >> 2) & 3) * 32 + (k0 >> 4) * 4 + (k0 & 3);
        #pragma unroll 4
        for (int it = 0; it < 64; ++it) {
            int r = w * 64 + it;
            unsigned val = *(const unsigned*)(wbf + r * 128 + k0);
            *(unsigned*)(ldsW + r * 128 + ((pBase + 8 * (r & 15)) & 127)) = val;
        }
    }

    // per-eval scalars (issue before the barrier)
    const float t  = tptr[0];
    const float dt = t / (float)NSTEP;
    const int   j  = 16 * w + m16;
    const int   c  = NSTEP - j;
    const float s  = samples_s[b * (NSTEP + 1) + c];
    const int   n  = samples_n[b * (NSTEP + 1) + c];
    const float dB = samples_dB[b * NSTEP + (NSTEP - 1 - j)];
    const float tk = (j == 0) ? t : t - dt * (float)(j - 1);

    __syncthreads();   // the only barrier

    // ---- layer 1: build B-fragments directly (h = 16kt + 4q + i) ----
    short4v Bv[8], Bd[8], Bdd[8];
    #pragma unroll
    for (int kt = 0; kt < 8; ++kt) {
        const int h0 = 16 * kt + 4 * q;
        float4 wa = *(const float4*)(W1 + h0);
        float4 wb = *(const float4*)(W1 + HIDDEN + h0);
        float4 bb = *(const float4*)(b1 + h0);
        float av[4], d1[4], d2[4];
        float wav[4] = {wa.x, wa.y, wa.z, wa.w};
        float wbv[4] = {wb.x, wb.y, wb.z, wb.w};
        float bbv[4] = {bb.x, bb.y, bb.z, bb.w};
        #pragma unroll
        for (int i = 0; i < 4; ++i) {
            float z  = fmaf(wav[i], s, fmaf(wbv[i], tk, bbv[i]));
            float a  = fast_tanh(z);
            float g  = 1.0f - a * a;
            float ad = g * wav[i];                  // z' = wa, z'' = 0
            float add = -2.0f * a * ad * wav[i];
            av[i] = a; d1[i] = ad; d2[i] = add;
        }
        Bv[kt]  = pack4(av[0], av[1], av[2], av[3]);
        Bd[kt]  = pack4(d1[0], d1[1], d1[2], d1[3]);
        Bdd[kt] = pack4(d2[0], d2[1], d2[2], d2[3]);
    }

    // ---- layer 2: per mt-tile MFMA + in-register epilogue -> next B-frags ----
    short4v Nv[8], Nd[8], Ndd[8];
    #pragma unroll
    for (int mt = 0; mt < 8; ++mt) {
        const short* lw = ldsW + (16 * mt + m16) * 128;
        f32x4 aV = {0.f,0.f,0.f,0.f}, aD = {0.f,0.f,0.f,0.f}, aDD = {0.f,0.f,0.f,0.f};
        #pragma unroll
        for (int kp = 0; kp < 4; ++kp) {            // kt pair (2kp, 2kp+1)
            int off = (q * 32 + kp * 8 + 8 * m16) & 127;
            short8v aw = *(const short8v*)(lw + off);
            short4v alo = (short4v){aw[0], aw[1], aw[2], aw[3]};
            short4v ahi = (short4v){aw[4], aw[5], aw[6], aw[7]};
            aV  = mfma16(alo, Bv [2*kp], aV );  aV  = mfma16(ahi, Bv [2*kp+1], aV );
            aD  = mfma16(alo, Bd [2*kp], aD );  aD  = mfma16(ahi, Bd [2*kp+1], aD );
            aDD = mfma16(alo, Bdd[2*kp], aDD);  aDD = mfma16(ahi, Bdd[2*kp+1], aDD);
        }
        const int h0 = 16 * mt + 4 * q;             // C: h = h0 + r  (r = reg)
        float4 bias = *(const float4*)(b2 + h0);
        float bv4[4] = {bias.x, bias.y, bias.z, bias.w};
        float a[4], d1[4], d2[4];
        #pragma unroll
        for (int r = 0; r < 4; ++r) {
            float z   = aV[r] + bv4[r];
            float zd  = aD[r];
            float zdd = aDD[r];
            float av  = fast_tanh(z);
            float g   = 1.0f - av * av;
            float ad  = g * zd;
            float add = fmaf(g, zdd, -2.0f * av * ad * zd);
            a[r] = av; d1[r] = ad; d2[r] = add;
        }
        Nv[mt]  = pack4(a[0], a[1], a[2], a[3]);    // == B-frag kt=mt of layer 3
        Nd[mt]  = pack4(d1[0], d1[1], d1[2], d1[3]);
        Ndd[mt] = pack4(d2[0], d2[1], d2[2], d2[3]);
    }

    // ---- layer 3 + fused layer 4 ----
    const short* __restrict__ w4t = wbf + 2 * HIDDEN * HIDDEN;
    float sv = 0.f, sd = 0.f, sdd = 0.f;
    #pragma unroll
    for (int mt = 0; mt < 8; ++mt) {
        const short* lw = ldsW + (HIDDEN + 16 * mt + m16) * 128;
        f32x4 aV = {0.f,0.f,0.f,0.f}, aD = {0.f,0.f,0.f,0.f}, aDD = {0.f,0.f,0.f,0.f};
        #pragma unroll
        for (int kp = 0; kp < 4; ++kp) {
            int off = (q * 32 + kp * 8 + 8 * m16) & 127;
            short8v aw = *(const short8v*)(lw + off);
            short4v alo = (short4v){aw[0], aw[1], aw[2], aw[3]};
            short4v ahi = (short4v){aw[4], aw[5], aw[6], aw[7]};
            aV  = mfma16(alo, Nv [2*kp], aV );  aV  = mfma16(ahi, Nv [2*kp+1], aV );
            aD  = mfma16(alo, Nd [2*kp], aD );  aD  = mfma16(ahi, Nd [2*kp+1], aD );
            aDD = mfma16(alo, Ndd[2*kp], aDD);  aDD = mfma16(ahi, Ndd[2*kp+1], aDD);
        }
        const int h0 = 16 * mt + 4 * q;
        float4 bias = *(const float4*)(b3 + h0);
        float bv4[4] = {bias.x, bias.y, bias.z, bias.w};
        uint2 w4u = *(const uint2*)(w4t + n * HIDDEN + h0);   // bf16 W4T[n][h0..h0+3]
        float wf[4];
        wf[0] = __uint_as_float(w4u.x << 16);
        wf[1] = __uint_as_float(w4u.x & 0xffff0000u);
        wf[2] = __uint_as_float(w4u.y << 16);
        wf[3] = __uint_as_float(w4u.y & 0xffff0000u);
        #pragma unroll
        for (int r = 0; r < 4; ++r) {
            float z   = aV[r] + bv4[r];
            float zd  = aD[r];
            float zdd = aDD[r];
            float av  = fast_tanh(z);
            float g   = 1.0f - av * av;
            float ad  = g * zd;
            float add = fmaf(g, zdd, -2.0f * av * ad * zd);
            sv  = fmaf(av,  wf[r], sv);
            sd  = fmaf(ad,  wf[r], sd);
            sdd = fmaf(add, wf[r], sdd);
        }
    }

    // ---- reduce across the 4 quads of each eval ----
    sd  += __shfl_xor(sd,  16, 64);  sd  += __shfl_xor(sd,  32, 64);
    sdd += __shfl_xor(sdd, 16, 64);  sdd += __shfl_xor(sdd, 32, 64);
    sv  += __shfl_xor(sv,  16, 64);  sv  += __shfl_xor(sv,  32, 64);

    float contrib = -(sd * dB + sdd * dt * 0.5f);
    if (j == 0) contrib += sv + b4[n];

    // sum the wave's 16 evals (each 16-lane group holds a duplicate set)
    contrib += __shfl_xor(contrib, 1, 64);
    contrib += __shfl_xor(contrib, 2, 64);
    contrib += __shfl_xor(contrib, 4, 64);
    contrib += __shfl_xor(contrib, 8, 64);
    if (lane == 0) atomicAdd(&out[b], contrib);
}

extern "C" void kernel_launch(void* const* d_in, const int* in_sizes, int n_in,
                              void* d_out, int out_size, void* d_ws, size_t ws_size,
                              hipStream_t stream) {
    const float* W1 = (const float*)d_in[0];
    const float* b1 = (const float*)d_in[1];
    const float* W2 = (const float*)d_in[2];
    const float* b2 = (const float*)d_in[3];
    const float* W3 = (const float*)d_in[4];
    const float* b3 = (const float*)d_in[5];
    const float* W4 = (const float*)d_in[6];
    const float* b4 = (const float*)d_in[7];
    const int*   sn  = (const int*)d_in[8];
    const float* ss  = (const float*)d_in[9];
    const float* sdB = (const float*)d_in[10];
    const float* t   = (const float*)d_in[11];
    float* out = (float*)d_out;
    short* wbf = (short*)d_ws;   // 90 KB: W2^T, W3^T, W4^T in bf16

    setup_kernel<<<(2 * HIDDEN * HIDDEN) / 256, 256, 0, stream>>>(W2, W3, W4, ss, wbf, out);
    eval_kernel<<<BATCH2, 256, 0, stream>>>(
        W1, b1, b2, b3, b4, wbf, sn, ss, sdB, t, out);
}

// Round 7
// 190.710 us; speedup vs baseline: 1.4469x; 1.0096x over previous
//
#include <hip/hip_runtime.h>
#include <math.h>

#define HIDDEN 128
#define NSTEP  64
#define BATCH2 4096
#define OUTD   100

typedef __attribute__((ext_vector_type(4))) short  short4v;
typedef __attribute__((ext_vector_type(8))) short  short8v;
typedef __attribute__((ext_vector_type(4))) float  f32x4;
typedef __attribute__((ext_vector_type(2))) float  f32x2;

// pack two f32 -> two bf16 (round-to-nearest, ties up); f0 in low short
static __device__ __forceinline__ unsigned pack2(float f0, float f1) {
    unsigned u0 = __float_as_uint(f0) + 0x8000u;
    unsigned u1 = __float_as_uint(f1) + 0x8000u;
    return __builtin_amdgcn_perm(u1, u0, 0x07060302u);
}
static __device__ __forceinline__ short4v pack4(float f0, float f1, float f2, float f3) {
    int2 p = { (int)pack2(f0, f1), (int)pack2(f2, f3) };
    return __builtin_bit_cast(short4v, p);
}
static __device__ __forceinline__ f32x4 mfma16(short4v a, short4v b, f32x4 c) {
    return __builtin_amdgcn_mfma_f32_16x16x16bf16_1k(a, b, c, 0, 0, 0);
}

// tanh value+1st+2nd tangent chain on a float2 pair.
// w = 2/(1+exp(2z)); a = 1-w; g = 1-a^2 = w*(2-w); ad = g*zd;
// add = g*zdd - 2*a*ad*zd.  __fdividef -> v_rcp_f32 + v_mul (no precise-div seq).
static __device__ __forceinline__ void tanh_chain2(
    f32x2 z, f32x2 zd, f32x2 zdd, f32x2& a, f32x2& ad, f32x2& add)
{
    f32x2 zz = z + z;
    f32x2 e  = { __expf(zz.x), __expf(zz.y) };
    f32x2 d  = e + (f32x2){1.f, 1.f};
    f32x2 wv = { __fdividef(2.0f, d.x), __fdividef(2.0f, d.y) };
    a = (f32x2){1.f, 1.f} - wv;
    f32x2 g = __builtin_elementwise_fma(-wv, wv, wv + wv);   // w*(2-w)
    ad = g * zd;
    f32x2 gz = g * zdd;
    f32x2 p  = a * zd;
    f32x2 u  = p + p;
    add = __builtin_elementwise_fma(-u, ad, gz);
}

// Setup: bf16-transpose W2/W3 (wbf) and W4 (w4t) into d_ws; init out.
// d_ws layout (shorts): [0..32767] = W2T,W3T (WT[n][k]); [32768..45567] = W4T[100][128]
__global__ __launch_bounds__(256) void setup_kernel(
    const float* __restrict__ W2, const float* __restrict__ W3,
    const float* __restrict__ W4,
    const float* __restrict__ samples_s,
    short* __restrict__ wbf, float* __restrict__ out)
{
    int t = blockIdx.x * blockDim.x + threadIdx.x;   // 0..32767
    int m = t >> 14, r = t & 16383, n = r >> 7, k = r & 127;
    const float* W = m ? W3 : W2;
    unsigned u = __float_as_uint(W[k * HIDDEN + n]) + 0x8000u;
    wbf[t] = (short)(u >> 16);
    if (t < OUTD * HIDDEN) {                         // W4T[n][h] = W4[h][n]
        int nn = t >> 7, h = t & 127;
        unsigned v = __float_as_uint(W4[h * OUTD + nn]) + 0x8000u;
        wbf[32768 + t] = (short)(v >> 16);
    }
    if (t < BATCH2) {
        out[t] = 0.0f;
        float s0 = samples_s[t * (NSTEP + 1)];
        out[BATCH2 + t] = 3.9894228040143267f * expf(-500000.0f * s0 * s0);
    }
}

// One block = one sample = 64 evals. Wave w owns evals j = 16w + (lane&15);
// quad q holds k-slice {16kt + 4q + i}. Activations stay in registers (K16
// C-frag == next layer's B-frag). Weights staged one layer at a time (32 KB
// LDS -> 4-5 blocks/CU instead of 2).
__global__ __launch_bounds__(256) void eval_kernel(
    const float* __restrict__ W1, const float* __restrict__ b1,
    const float* __restrict__ b2, const float* __restrict__ b3,
    const float* __restrict__ b4,
    const short* __restrict__ wbf,
    const int*   __restrict__ samples_n,
    const float* __restrict__ samples_s,
    const float* __restrict__ samples_dB,
    const float* __restrict__ tptr,
    float* __restrict__ out)
{
    // One layer's weights, permuted:
    // ldsW[r*128 + ((q*32 + kt*4 + i + 8*(r&15)) & 127)] = WT[r][16kt + 4q + i]
    __shared__ short ldsW[HIDDEN * HIDDEN];   // 32 KB

    const int tid  = threadIdx.x;
    const int w    = tid >> 6;
    const int lane = tid & 63;
    const int m16  = lane & 15;
    const int q    = lane >> 4;
    const int b    = blockIdx.x;

    const int k0    = 2 * lane;
    const int pBase = ((k0 >> 2) & 3) * 32 + (k0 >> 4) * 4 + (k0 & 3);

    // ---- stage layer-2 weights (wave w: rows 32w..32w+31) ----
    #pragma unroll 4
    for (int it = 0; it < 32; ++it) {
        int r = w * 32 + it;
        unsigned val = *(const unsigned*)(wbf + r * 128 + k0);
        *(unsigned*)(ldsW + r * 128 + ((pBase + 8 * (r & 15)) & 127)) = val;
    }

    // per-eval scalars
    const float t  = tptr[0];
    const float dt = t / (float)NSTEP;
    const int   j  = 16 * w + m16;
    const int   c  = NSTEP - j;
    const float s  = samples_s[b * (NSTEP + 1) + c];
    const int   n  = samples_n[b * (NSTEP + 1) + c];
    const float dB = samples_dB[b * NSTEP + (NSTEP - 1 - j)];
    const float tk = (j == 0) ? t : t - dt * (float)(j - 1);

    // ---- layer 1: build B-fragments in registers (h = 16kt + 4q + i) ----
    short4v Bv[8], Bd[8], Bdd[8];
    #pragma unroll
    for (int kt = 0; kt < 8; ++kt) {
        const int h0 = 16 * kt + 4 * q;
        float4 wa = *(const float4*)(W1 + h0);
        float4 wb = *(const float4*)(W1 + HIDDEN + h0);
        float4 bb = *(const float4*)(b1 + h0);
        f32x2 z0 = { fmaf(wa.x, s, fmaf(wb.x, tk, bb.x)),
                     fmaf(wa.y, s, fmaf(wb.y, tk, bb.y)) };
        f32x2 z1 = { fmaf(wa.z, s, fmaf(wb.z, tk, bb.z)),
                     fmaf(wa.w, s, fmaf(wb.w, tk, bb.w)) };
        f32x2 a0, ad0, add0, a1, ad1, add1;
        tanh_chain2(z0, (f32x2){wa.x, wa.y}, (f32x2){0.f, 0.f}, a0, ad0, add0);
        tanh_chain2(z1, (f32x2){wa.z, wa.w}, (f32x2){0.f, 0.f}, a1, ad1, add1);
        Bv[kt]  = pack4(a0.x,  a0.y,  a1.x,  a1.y);
        Bd[kt]  = pack4(ad0.x, ad0.y, ad1.x, ad1.y);
        Bdd[kt] = pack4(add0.x, add0.y, add1.x, add1.y);
    }

    __syncthreads();   // layer-2 weights visible

    // ---- layer 2: MFMA + in-register epilogue -> next B-frags ----
    short4v Nv[8], Nd[8], Ndd[8];
    #pragma unroll
    for (int mt = 0; mt < 8; ++mt) {
        const short* lw = ldsW + (16 * mt + m16) * 128;
        f32x4 aV = {0.f,0.f,0.f,0.f}, aD = {0.f,0.f,0.f,0.f}, aDD = {0.f,0.f,0.f,0.f};
        #pragma unroll
        for (int kp = 0; kp < 4; ++kp) {
            int off = (q * 32 + kp * 8 + 8 * m16) & 127;
            short8v aw = *(const short8v*)(lw + off);
            short4v alo = (short4v){aw[0], aw[1], aw[2], aw[3]};
            short4v ahi = (short4v){aw[4], aw[5], aw[6], aw[7]};
            aV  = mfma16(alo, Bv [2*kp], aV );  aV  = mfma16(ahi, Bv [2*kp+1], aV );
            aD  = mfma16(alo, Bd [2*kp], aD );  aD  = mfma16(ahi, Bd [2*kp+1], aD );
            aDD = mfma16(alo, Bdd[2*kp], aDD);  aDD = mfma16(ahi, Bdd[2*kp+1], aDD);
        }
        const int h0 = 16 * mt + 4 * q;            // C: h = h0 + r
        float4 bias = *(const float4*)(b2 + h0);
        f32x2 a0, ad0, add0, a1, ad1, add1;
        tanh_chain2((f32x2){aV[0] + bias.x, aV[1] + bias.y},
                    (f32x2){aD[0], aD[1]}, (f32x2){aDD[0], aDD[1]}, a0, ad0, add0);
        tanh_chain2((f32x2){aV[2] + bias.z, aV[3] + bias.w},
                    (f32x2){aD[2], aD[3]}, (f32x2){aDD[2], aDD[3]}, a1, ad1, add1);
        Nv[mt]  = pack4(a0.x,  a0.y,  a1.x,  a1.y);   // == B-frag kt=mt of layer 3
        Nd[mt]  = pack4(ad0.x, ad0.y, ad1.x, ad1.y);
        Ndd[mt] = pack4(add0.x, add0.y, add1.x, add1.y);
    }

    __syncthreads();   // layer-2 weight reads done

    // ---- stage layer-3 weights ----
    #pragma unroll 4
    for (int it = 0; it < 32; ++it) {
        int r = w * 32 + it;
        unsigned val = *(const unsigned*)(wbf + HIDDEN * HIDDEN + r * 128 + k0);
        *(unsigned*)(ldsW + r * 128 + ((pBase + 8 * (r & 15)) & 127)) = val;
    }
    __syncthreads();   // layer-3 weights visible

    // ---- layer 3 + fused layer 4 ----
    const short* __restrict__ w4t = wbf + 2 * HIDDEN * HIDDEN;
    float sv = 0.f, sd = 0.f, sdd = 0.f;
    #pragma unroll
    for (int mt = 0; mt < 8; ++mt) {
        const short* lw = ldsW + (16 * mt + m16) * 128;
        f32x4 aV = {0.f,0.f,0.f,0.f}, aD = {0.f,0.f,0.f,0.f}, aDD = {0.f,0.f,0.f,0.f};
        #pragma unroll
        for (int kp = 0; kp < 4; ++kp) {
            int off = (q * 32 + kp * 8 + 8 * m16) & 127;
            short8v aw = *(const short8v*)(lw + off);
            short4v alo = (short4v){aw[0], aw[1], aw[2], aw[3]};
            short4v ahi = (short4v){aw[4], aw[5], aw[6], aw[7]};
            aV  = mfma16(alo, Nv [2*kp], aV );  aV  = mfma16(ahi, Nv [2*kp+1], aV );
            aD  = mfma16(alo, Nd [2*kp], aD );  aD  = mfma16(ahi, Nd [2*kp+1], aD );
            aDD = mfma16(alo, Ndd[2*kp], aDD);  aDD = mfma16(ahi, Ndd[2*kp+1], aDD);
        }
        const int h0 = 16 * mt + 4 * q;
        float4 bias = *(const float4*)(b3 + h0);
        uint2 w4u = *(const uint2*)(w4t + n * HIDDEN + h0);   // bf16 W4T[n][h0..h0+3]
        float wf0 = __uint_as_float(w4u.x << 16);
        float wf1 = __uint_as_float(w4u.x & 0xffff0000u);
        float wf2 = __uint_as_float(w4u.y << 16);
        float wf3 = __uint_as_float(w4u.y & 0xffff0000u);
        f32x2 a0, ad0, add0, a1, ad1, add1;
        tanh_chain2((f32x2){aV[0] + bias.x, aV[1] + bias.y},
                    (f32x2){aD[0], aD[1]}, (f32x2){aDD[0], aDD[1]}, a0, ad0, add0);
        tanh_chain2((f32x2){aV[2] + bias.z, aV[3] + bias.w},
                    (f32x2){aD[2], aD[3]}, (f32x2){aDD[2], aDD[3]}, a1, ad1, add1);
        sv  = fmaf(a0.x,  wf0, fmaf(a0.y,  wf1, fmaf(a1.x,  wf2, fmaf(a1.y,  wf3, sv))));
        sd  = fmaf(ad0.x, wf0, fmaf(ad0.y, wf1, fmaf(ad1.x, wf2, fmaf(ad1.y, wf3, sd))));
        sdd = fmaf(add0.x, wf0, fmaf(add0.y, wf1, fmaf(add1.x, wf2, fmaf(add1.y, wf3, sdd))));
    }

    // ---- reduce across the 4 quads of each eval ----
    sd  += __shfl_xor(sd,  16, 64);  sd  += __shfl_xor(sd,  32, 64);
    sdd += __shfl_xor(sdd, 16, 64);  sdd += __shfl_xor(sdd, 32, 64);
    sv  += __shfl_xor(sv,  16, 64);  sv  += __shfl_xor(sv,  32, 64);

    float contrib = -(sd * dB + sdd * dt * 0.5f);
    if (j == 0) contrib += sv + b4[n];

    // sum the wave's 16 evals (each 16-lane group holds a duplicate set)
    contrib += __shfl_xor(contrib, 1, 64);
    contrib += __shfl_xor(contrib, 2, 64);
    contrib += __shfl_xor(contrib, 4, 64);
    contrib += __shfl_xor(contrib, 8, 64);
    if (lane == 0) atomicAdd(&out[b], contrib);
}

extern "C" void kernel_launch(void* const* d_in, const int* in_sizes, int n_in,
                              void* d_out, int out_size, void* d_ws, size_t ws_size,
                              hipStream_t stream) {
    const float* W1 = (const float*)d_in[0];
    const float* b1 = (const float*)d_in[1];
    const float* W2 = (const float*)d_in[2];
    const float* b2 = (const float*)d_in[3];
    const float* W3 = (const float*)d_in[4];
    const float* b3 = (const float*)d_in[5];
    const float* W4 = (const float*)d_in[6];
    const float* b4 = (const float*)d_in[7];
    const int*   sn  = (const int*)d_in[8];
    const float* ss  = (const float*)d_in[9];
    const float* sdB = (const float*)d_in[10];
    const float* t   = (const float*)d_in[11];
    float* out = (float*)d_out;
    short* wbf = (short*)d_ws;   // 90 KB: W2^T, W3^T, W4^T in bf16

    setup_kernel<<<(2 * HIDDEN * HIDDEN) / 256, 256, 0, stream>>>(W2, W3, W4, ss, wbf, out);
    eval_kernel<<<BATCH2, 256, 0, stream>>>(
        W1, b1, b2, b3, b4, wbf, sn, ss, sdB, t, out);
}

// Round 8
// 176.166 us; speedup vs baseline: 1.5664x; 1.0826x over previous
//
#include <hip/hip_runtime.h>
#include <hip/hip_fp16.h>
#include <math.h>

#define HIDDEN 128
#define NSTEP  64
#define BATCH2 4096
#define OUTD   100

typedef __attribute__((ext_vector_type(4))) _Float16 f16x4;
typedef __attribute__((ext_vector_type(8))) _Float16 f16x8;
typedef __attribute__((ext_vector_type(4))) float    f32x4;

static __device__ __forceinline__ f32x4 mfma16(f16x4 a, f16x4 b, f32x4 c) {
    return __builtin_amdgcn_mfma_f32_16x16x16f16(a, b, c, 0, 0, 0);
}
static __device__ __forceinline__ unsigned h2u(__half2 h) {
    return __builtin_bit_cast(unsigned, h);
}
static __device__ __forceinline__ __half2 u2h(unsigned u) {
    return __builtin_bit_cast(__half2, u);
}
static __device__ __forceinline__ f16x4 frag2(__half2 lo, __half2 hi) {
    uint2 p = { h2u(lo), h2u(hi) };
    return __builtin_bit_cast(f16x4, p);
}

// packed-f16 tanh value+1st+2nd tangent chain (2 units per call)
// w = 2/(1+e^{2z}); a = 1-w; g = w(2-w); ad = g zd; add = g zdd - 2 a zd ad
static __device__ __forceinline__ void tanh_chain_h2(
    __half2 z, __half2 zd, __half2 zdd,
    __half2& a, __half2& ad, __half2& add)
{
    const __half2 one = __float2half2_rn(1.0f);
    const __half2 two = __float2half2_rn(2.0f);
    __half2 e = h2exp(__hadd2(z, z));
    __half2 w = __hmul2(two, h2rcp(__hadd2(e, one)));
    a  = __hsub2(one, w);
    __half2 g = __hmul2(w, __hsub2(two, w));
    ad = __hmul2(g, zd);
    __half2 p = __hmul2(a, zd);
    __half2 u = __hadd2(p, p);
    add = __hsub2(__hmul2(g, zdd), __hmul2(u, ad));
}

// Setup: f16-transpose W2/W3 (wbf) and W4 (w4t) into d_ws; init out.
// d_ws layout (halfs): [0..32767] = W2T,W3T (WT[n][k]); [32768..45567] = W4T[100][128]
__global__ __launch_bounds__(256) void setup_kernel(
    const float* __restrict__ W2, const float* __restrict__ W3,
    const float* __restrict__ W4,
    const float* __restrict__ samples_s,
    __half* __restrict__ wbf, float* __restrict__ out)
{
    int t = blockIdx.x * blockDim.x + threadIdx.x;   // 0..32767
    int m = t >> 14, r = t & 16383, n = r >> 7, k = r & 127;
    const float* W = m ? W3 : W2;
    wbf[t] = __float2half(W[k * HIDDEN + n]);
    if (t < OUTD * HIDDEN) {                         // W4T[n][h] = W4[h][n]
        int nn = t >> 7, h = t & 127;
        wbf[32768 + t] = __float2half(W4[h * OUTD + nn]);
    }
    if (t < BATCH2) {
        out[t] = 0.0f;
        float s0 = samples_s[t * (NSTEP + 1)];
        out[BATCH2 + t] = 3.9894228040143267f * expf(-500000.0f * s0 * s0);
    }
}

// One block = one sample = 64 evals. Wave w owns evals j = 16w + (lane&15);
// quad q holds k-slice {16kt + 4q + i}. Activations stay in registers as
// packed f16 (K16 C-frag == next layer's B-frag). Weights staged one layer
// at a time (32 KB LDS).
__global__ __launch_bounds__(256) void eval_kernel(
    const float* __restrict__ W1, const float* __restrict__ b1,
    const float* __restrict__ b2, const float* __restrict__ b3,
    const float* __restrict__ b4,
    const __half* __restrict__ wbf,
    const int*   __restrict__ samples_n,
    const float* __restrict__ samples_s,
    const float* __restrict__ samples_dB,
    const float* __restrict__ tptr,
    float* __restrict__ out)
{
    // One layer's weights, permuted:
    // ldsW[r*128 + ((q*32 + kt*4 + i + 8*(r&15)) & 127)] = WT[r][16kt + 4q + i]
    __shared__ short ldsW[HIDDEN * HIDDEN];   // 32 KB (f16 payload)

    const int tid  = threadIdx.x;
    const int w    = tid >> 6;
    const int lane = tid & 63;
    const int m16  = lane & 15;
    const int q    = lane >> 4;
    const int b    = blockIdx.x;

    const int k0    = 2 * lane;
    const int pBase = ((k0 >> 2) & 3) * 32 + (k0 >> 4) * 4 + (k0 & 3);

    // ---- stage layer-2 weights (wave w: rows 32w..32w+31) ----
    #pragma unroll 4
    for (int it = 0; it < 32; ++it) {
        int r = w * 32 + it;
        unsigned val = *(const unsigned*)((const short*)wbf + r * 128 + k0);
        *(unsigned*)(ldsW + r * 128 + ((pBase + 8 * (r & 15)) & 127)) = val;
    }

    // per-eval scalars
    const float t  = tptr[0];
    const float dt = t / (float)NSTEP;
    const int   j  = 16 * w + m16;
    const int   c  = NSTEP - j;
    const float s  = samples_s[b * (NSTEP + 1) + c];
    const int   n  = samples_n[b * (NSTEP + 1) + c];
    const float dB = samples_dB[b * NSTEP + (NSTEP - 1 - j)];
    const float tk = (j == 0) ? t : t - dt * (float)(j - 1);

    // ---- layer 1: build packed-f16 B-fragments (h = 16kt + 4q + i) ----
    f16x4 Bv[8], Bd[8], Bdd[8];
    const __half2 zero2 = __float2half2_rn(0.0f);
    #pragma unroll
    for (int kt = 0; kt < 8; ++kt) {
        const int h0 = 16 * kt + 4 * q;
        float4 wa = *(const float4*)(W1 + h0);
        float4 wb = *(const float4*)(W1 + HIDDEN + h0);
        float4 bb = *(const float4*)(b1 + h0);
        __half2 z0 = __floats2half2_rn(fmaf(wa.x, s, fmaf(wb.x, tk, bb.x)),
                                       fmaf(wa.y, s, fmaf(wb.y, tk, bb.y)));
        __half2 z1 = __floats2half2_rn(fmaf(wa.z, s, fmaf(wb.z, tk, bb.z)),
                                       fmaf(wa.w, s, fmaf(wb.w, tk, bb.w)));
        __half2 zd0 = __floats2half2_rn(wa.x, wa.y);
        __half2 zd1 = __floats2half2_rn(wa.z, wa.w);
        __half2 a0, ad0, add0, a1, ad1, add1;
        tanh_chain_h2(z0, zd0, zero2, a0, ad0, add0);
        tanh_chain_h2(z1, zd1, zero2, a1, ad1, add1);
        Bv[kt]  = frag2(a0,  a1);
        Bd[kt]  = frag2(ad0, ad1);
        Bdd[kt] = frag2(add0, add1);
    }

    __syncthreads();   // layer-2 weights visible

    // ---- layer 2: MFMA + packed-f16 epilogue -> next B-frags ----
    f16x4 Nv[8], Nd[8], Ndd[8];
    #pragma unroll
    for (int mt = 0; mt < 8; ++mt) {
        const short* lw = ldsW + (16 * mt + m16) * 128;
        f32x4 aV = {0.f,0.f,0.f,0.f}, aD = {0.f,0.f,0.f,0.f}, aDD = {0.f,0.f,0.f,0.f};
        #pragma unroll
        for (int kp = 0; kp < 4; ++kp) {
            int off = (q * 32 + kp * 8 + 8 * m16) & 127;
            f16x8 aw = *(const f16x8*)(lw + off);
            f16x4 alo = (f16x4){aw[0], aw[1], aw[2], aw[3]};
            f16x4 ahi = (f16x4){aw[4], aw[5], aw[6], aw[7]};
            aV  = mfma16(alo, Bv [2*kp], aV );
            aD  = mfma16(alo, Bd [2*kp], aD );
            aDD = mfma16(alo, Bdd[2*kp], aDD);
            aV  = mfma16(ahi, Bv [2*kp+1], aV );
            aD  = mfma16(ahi, Bd [2*kp+1], aD );
            aDD = mfma16(ahi, Bdd[2*kp+1], aDD);
        }
        const int h0 = 16 * mt + 4 * q;            // C: h = h0 + r
        float4 bias = *(const float4*)(b2 + h0);
        __half2 a0, ad0, add0, a1, ad1, add1;
        tanh_chain_h2(__floats2half2_rn(aV[0] + bias.x, aV[1] + bias.y),
                      __floats2half2_rn(aD[0], aD[1]),
                      __floats2half2_rn(aDD[0], aDD[1]), a0, ad0, add0);
        tanh_chain_h2(__floats2half2_rn(aV[2] + bias.z, aV[3] + bias.w),
                      __floats2half2_rn(aD[2], aD[3]),
                      __floats2half2_rn(aDD[2], aDD[3]), a1, ad1, add1);
        Nv[mt]  = frag2(a0,  a1);                  // == B-frag kt=mt of layer 3
        Nd[mt]  = frag2(ad0, ad1);
        Ndd[mt] = frag2(add0, add1);
    }

    __syncthreads();   // layer-2 weight reads done

    // ---- stage layer-3 weights ----
    #pragma unroll 4
    for (int it = 0; it < 32; ++it) {
        int r = w * 32 + it;
        unsigned val = *(const unsigned*)((const short*)wbf + HIDDEN * HIDDEN + r * 128 + k0);
        *(unsigned*)(ldsW + r * 128 + ((pBase + 8 * (r & 15)) & 127)) = val;
    }
    __syncthreads();   // layer-3 weights visible

    // ---- layer 3 + fused layer 4 (packed-f16 dot) ----
    const __half* __restrict__ w4t = wbf + 2 * HIDDEN * HIDDEN;
    __half2 accV = zero2, accD = zero2, accDD = zero2;
    #pragma unroll
    for (int mt = 0; mt < 8; ++mt) {
        const short* lw = ldsW + (16 * mt + m16) * 128;
        f32x4 aV = {0.f,0.f,0.f,0.f}, aD = {0.f,0.f,0.f,0.f}, aDD = {0.f,0.f,0.f,0.f};
        #pragma unroll
        for (int kp = 0; kp < 4; ++kp) {
            int off = (q * 32 + kp * 8 + 8 * m16) & 127;
            f16x8 aw = *(const f16x8*)(lw + off);
            f16x4 alo = (f16x4){aw[0], aw[1], aw[2], aw[3]};
            f16x4 ahi = (f16x4){aw[4], aw[5], aw[6], aw[7]};
            aV  = mfma16(alo, Nv [2*kp], aV );
            aD  = mfma16(alo, Nd [2*kp], aD );
            aDD = mfma16(alo, Ndd[2*kp], aDD);
            aV  = mfma16(ahi, Nv [2*kp+1], aV );
            aD  = mfma16(ahi, Nd [2*kp+1], aD );
            aDD = mfma16(ahi, Ndd[2*kp+1], aDD);
        }
        const int h0 = 16 * mt + 4 * q;
        float4 bias = *(const float4*)(b3 + h0);
        uint2 w4u = *(const uint2*)(w4t + n * HIDDEN + h0);   // f16 W4T[n][h0..h0+3]
        __half2 w4lo = u2h(w4u.x), w4hi = u2h(w4u.y);
        __half2 a0, ad0, add0, a1, ad1, add1;
        tanh_chain_h2(__floats2half2_rn(aV[0] + bias.x, aV[1] + bias.y),
                      __floats2half2_rn(aD[0], aD[1]),
                      __floats2half2_rn(aDD[0], aDD[1]), a0, ad0, add0);
        tanh_chain_h2(__floats2half2_rn(aV[2] + bias.z, aV[3] + bias.w),
                      __floats2half2_rn(aD[2], aD[3]),
                      __floats2half2_rn(aDD[2], aDD[3]), a1, ad1, add1);
        accV  = __hfma2(a0,  w4lo, accV );  accV  = __hfma2(a1,  w4hi, accV );
        accD  = __hfma2(ad0, w4lo, accD );  accD  = __hfma2(ad1, w4hi, accD );
        accDD = __hfma2(add0, w4lo, accDD); accDD = __hfma2(add1, w4hi, accDD);
    }
    float sv  = __low2float(accV)  + __high2float(accV);
    float sd  = __low2float(accD)  + __high2float(accD);
    float sdd = __low2float(accDD) + __high2float(accDD);

    // ---- reduce across the 4 quads of each eval ----
    sd  += __shfl_xor(sd,  16, 64);  sd  += __shfl_xor(sd,  32, 64);
    sdd += __shfl_xor(sdd, 16, 64);  sdd += __shfl_xor(sdd, 32, 64);
    sv  += __shfl_xor(sv,  16, 64);  sv  += __shfl_xor(sv,  32, 64);

    float contrib = -(sd * dB + sdd * dt * 0.5f);
    if (j == 0) contrib += sv + b4[n];

    // sum the wave's 16 evals (each 16-lane group holds a duplicate set)
    contrib += __shfl_xor(contrib, 1, 64);
    contrib += __shfl_xor(contrib, 2, 64);
    contrib += __shfl_xor(contrib, 4, 64);
    contrib += __shfl_xor(contrib, 8, 64);
    if (lane == 0) atomicAdd(&out[b], contrib);
}

extern "C" void kernel_launch(void* const* d_in, const int* in_sizes, int n_in,
                              void* d_out, int out_size, void* d_ws, size_t ws_size,
                              hipStream_t stream) {
    const float* W1 = (const float*)d_in[0];
    const float* b1 = (const float*)d_in[1];
    const float* W2 = (const float*)d_in[2];
    const float* b2 = (const float*)d_in[3];
    const float* W3 = (const float*)d_in[4];
    const float* b3 = (const float*)d_in[5];
    const float* W4 = (const float*)d_in[6];
    const float* b4 = (const float*)d_in[7];
    const int*   sn  = (const int*)d_in[8];
    const float* ss  = (const float*)d_in[9];
    const float* sdB = (const float*)d_in[10];
    const float* t   = (const float*)d_in[11];
    float* out = (float*)d_out;
    __half* wbf = (__half*)d_ws;   // 90 KB: W2^T, W3^T, W4^T in f16

    setup_kernel<<<(2 * HIDDEN * HIDDEN) / 256, 256, 0, stream>>>(W2, W3, W4, ss, wbf, out);
    eval_kernel<<<BATCH2, 256, 0, stream>>>(
        W1, b1, b2, b3, b4, wbf, sn, ss, sdB, t, out);
}

// Round 9
// 165.404 us; speedup vs baseline: 1.6683x; 1.0651x over previous
//
#include <hip/hip_runtime.h>
#include <hip/hip_fp16.h>
#include <math.h>

#define HIDDEN 128
#define NSTEP  64
#define BATCH2 4096
#define OUTD   100

typedef __attribute__((ext_vector_type(4))) _Float16 f16x4;
typedef __attribute__((ext_vector_type(8))) _Float16 f16x8;
typedef __attribute__((ext_vector_type(4))) float    f32x4;

static __device__ __forceinline__ f32x4 mfma16(f16x4 a, f16x4 b, f32x4 c) {
    return __builtin_amdgcn_mfma_f32_16x16x16f16(a, b, c, 0, 0, 0);
}
static __device__ __forceinline__ unsigned h2u(__half2 h) {
    return __builtin_bit_cast(unsigned, h);
}
static __device__ __forceinline__ __half2 u2h(unsigned u) {
    return __builtin_bit_cast(__half2, u);
}
static __device__ __forceinline__ f16x4 frag2(__half2 lo, __half2 hi) {
    uint2 p = { h2u(lo), h2u(hi) };
    return __builtin_bit_cast(f16x4, p);
}

// packed-f16 tanh value+1st+2nd tangent chain (2 units per call)
// w = 2/(1+e^{2z}); a = 1-w; g = w(2-w); ad = g zd; add = g zdd - 2 a zd ad
static __device__ __forceinline__ void tanh_chain_h2(
    __half2 z, __half2 zd, __half2 zdd,
    __half2& a, __half2& ad, __half2& add)
{
    const __half2 one = __float2half2_rn(1.0f);
    const __half2 two = __float2half2_rn(2.0f);
    __half2 e = h2exp(__hadd2(z, z));
    __half2 w = __hmul2(two, h2rcp(__hadd2(e, one)));
    a  = __hsub2(one, w);
    __half2 g = __hmul2(w, __hsub2(two, w));
    ad = __hmul2(g, zd);
    __half2 p = __hmul2(a, zd);
    __half2 u = __hadd2(p, p);
    add = __hsub2(__hmul2(g, zdd), __hmul2(u, ad));
}

// Setup: f16-transpose W2/W3 (wbf) and W4 (w4t) into d_ws; init out.
// d_ws layout (halfs): [0..32767] = W2T,W3T (WT[n][k]); [32768..45567] = W4T[100][128]
__global__ __launch_bounds__(256) void setup_kernel(
    const float* __restrict__ W2, const float* __restrict__ W3,
    const float* __restrict__ W4,
    const float* __restrict__ samples_s,
    __half* __restrict__ wbf, float* __restrict__ out)
{
    int t = blockIdx.x * blockDim.x + threadIdx.x;   // 0..32767
    int m = t >> 14, r = t & 16383, n = r >> 7, k = r & 127;
    const float* W = m ? W3 : W2;
    wbf[t] = __float2half(W[k * HIDDEN + n]);
    if (t < OUTD * HIDDEN) {                         // W4T[n][h] = W4[h][n]
        int nn = t >> 7, h = t & 127;
        wbf[32768 + t] = __float2half(W4[h * OUTD + nn]);
    }
    if (t < BATCH2) {
        out[t] = 0.0f;
        float s0 = samples_s[t * (NSTEP + 1)];
        out[BATCH2 + t] = 3.9894228040143267f * expf(-500000.0f * s0 * s0);
    }
}

// One block = one sample = 64 evals. Wave w owns evals j = 16w + (lane&15);
// quad q holds k-slice {16kt + 4q + i}. Activations stay in registers as
// packed f16 (K16 C-frag == next layer's B-frag). Weights staged one layer
// at a time (32 KB LDS). __launch_bounds__(256,3): cap reg budget at
// ~170/wave so 3 waves/SIMD fit (R8 ran at 2 waves/SIMD: AGPR overflow).
__global__ __launch_bounds__(256, 3) void eval_kernel(
    const float* __restrict__ W1, const float* __restrict__ b1,
    const float* __restrict__ b2, const float* __restrict__ b3,
    const float* __restrict__ b4,
    const __half* __restrict__ wbf,
    const int*   __restrict__ samples_n,
    const float* __restrict__ samples_s,
    const float* __restrict__ samples_dB,
    const float* __restrict__ tptr,
    float* __restrict__ out)
{
    // One layer's weights, permuted:
    // ldsW[r*128 + ((q*32 + kt*4 + i + 8*(r&15)) & 127)] = WT[r][16kt + 4q + i]
    __shared__ short ldsW[HIDDEN * HIDDEN];   // 32 KB (f16 payload)
    __shared__ float ldsB2[HIDDEN];           // biases staged once (epilogue
    __shared__ float ldsB3[HIDDEN];           // critical path: LDS < L2 latency)

    const int tid  = threadIdx.x;
    const int w    = tid >> 6;
    const int lane = tid & 63;
    const int m16  = lane & 15;
    const int q    = lane >> 4;
    const int b    = blockIdx.x;

    const int k0    = 2 * lane;
    const int pBase = ((k0 >> 2) & 3) * 32 + (k0 >> 4) * 4 + (k0 & 3);

    // ---- stage layer-2 weights (wave w: rows 32w..32w+31) + biases ----
    if (tid < HIDDEN) {
        ldsB2[tid] = b2[tid];
        ldsB3[tid] = b3[tid];
    }
    #pragma unroll 4
    for (int it = 0; it < 32; ++it) {
        int r = w * 32 + it;
        unsigned val = *(const unsigned*)((const short*)wbf + r * 128 + k0);
        *(unsigned*)(ldsW + r * 128 + ((pBase + 8 * (r & 15)) & 127)) = val;
    }

    // per-eval scalars
    const float t  = tptr[0];
    const float dt = t / (float)NSTEP;
    const int   j  = 16 * w + m16;
    const int   c  = NSTEP - j;
    const float s  = samples_s[b * (NSTEP + 1) + c];
    const int   n  = samples_n[b * (NSTEP + 1) + c];
    const float dB = samples_dB[b * NSTEP + (NSTEP - 1 - j)];
    const float tk = (j == 0) ? t : t - dt * (float)(j - 1);

    // ---- layer 1: build packed-f16 B-fragments (h = 16kt + 4q + i) ----
    f16x4 Bv[8], Bd[8], Bdd[8];
    const __half2 zero2 = __float2half2_rn(0.0f);
    #pragma unroll
    for (int kt = 0; kt < 8; ++kt) {
        const int h0 = 16 * kt + 4 * q;
        float4 wa = *(const float4*)(W1 + h0);
        float4 wb = *(const float4*)(W1 + HIDDEN + h0);
        float4 bb = *(const float4*)(b1 + h0);
        __half2 z0 = __floats2half2_rn(fmaf(wa.x, s, fmaf(wb.x, tk, bb.x)),
                                       fmaf(wa.y, s, fmaf(wb.y, tk, bb.y)));
        __half2 z1 = __floats2half2_rn(fmaf(wa.z, s, fmaf(wb.z, tk, bb.z)),
                                       fmaf(wa.w, s, fmaf(wb.w, tk, bb.w)));
        __half2 zd0 = __floats2half2_rn(wa.x, wa.y);
        __half2 zd1 = __floats2half2_rn(wa.z, wa.w);
        __half2 a0, ad0, add0, a1, ad1, add1;
        tanh_chain_h2(z0, zd0, zero2, a0, ad0, add0);
        tanh_chain_h2(z1, zd1, zero2, a1, ad1, add1);
        Bv[kt]  = frag2(a0,  a1);
        Bd[kt]  = frag2(ad0, ad1);
        Bdd[kt] = frag2(add0, add1);
    }

    __syncthreads();   // layer-2 weights + biases visible

    // ---- layer 2: MFMA + packed-f16 epilogue -> next B-frags ----
    f16x4 Nv[8], Nd[8], Ndd[8];
    #pragma unroll
    for (int mt = 0; mt < 8; ++mt) {
        const short* lw = ldsW + (16 * mt + m16) * 128;
        f32x4 aV = {0.f,0.f,0.f,0.f}, aD = {0.f,0.f,0.f,0.f}, aDD = {0.f,0.f,0.f,0.f};
        #pragma unroll
        for (int kp = 0; kp < 4; ++kp) {
            int off = (q * 32 + kp * 8 + 8 * m16) & 127;
            f16x8 aw = *(const f16x8*)(lw + off);
            f16x4 alo = (f16x4){aw[0], aw[1], aw[2], aw[3]};
            f16x4 ahi = (f16x4){aw[4], aw[5], aw[6], aw[7]};
            aV  = mfma16(alo, Bv [2*kp], aV );
            aD  = mfma16(alo, Bd [2*kp], aD );
            aDD = mfma16(alo, Bdd[2*kp], aDD);
            aV  = mfma16(ahi, Bv [2*kp+1], aV );
            aD  = mfma16(ahi, Bd [2*kp+1], aD );
            aDD = mfma16(ahi, Bdd[2*kp+1], aDD);
        }
        const int h0 = 16 * mt + 4 * q;            // C: h = h0 + r
        float4 bias = *(const float4*)(ldsB2 + h0);
        __half2 a0, ad0, add0, a1, ad1, add1;
        tanh_chain_h2(__floats2half2_rn(aV[0] + bias.x, aV[1] + bias.y),
                      __floats2half2_rn(aD[0], aD[1]),
                      __floats2half2_rn(aDD[0], aDD[1]), a0, ad0, add0);
        tanh_chain_h2(__floats2half2_rn(aV[2] + bias.z, aV[3] + bias.w),
                      __floats2half2_rn(aD[2], aD[3]),
                      __floats2half2_rn(aDD[2], aDD[3]), a1, ad1, add1);
        Nv[mt]  = frag2(a0,  a1);                  // == B-frag kt=mt of layer 3
        Nd[mt]  = frag2(ad0, ad1);
        Ndd[mt] = frag2(add0, add1);
    }

    __syncthreads();   // layer-2 weight reads done

    // ---- stage layer-3 weights ----
    #pragma unroll 4
    for (int it = 0; it < 32; ++it) {
        int r = w * 32 + it;
        unsigned val = *(const unsigned*)((const short*)wbf + HIDDEN * HIDDEN + r * 128 + k0);
        *(unsigned*)(ldsW + r * 128 + ((pBase + 8 * (r & 15)) & 127)) = val;
    }
    __syncthreads();   // layer-3 weights visible

    // ---- layer 3 + fused layer 4 (packed-f16 dot) ----
    const __half* __restrict__ w4t = wbf + 2 * HIDDEN * HIDDEN;
    __half2 accV = zero2, accD = zero2, accDD = zero2;
    #pragma unroll
    for (int mt = 0; mt < 8; ++mt) {
        const short* lw = ldsW + (16 * mt + m16) * 128;
        f32x4 aV = {0.f,0.f,0.f,0.f}, aD = {0.f,0.f,0.f,0.f}, aDD = {0.f,0.f,0.f,0.f};
        #pragma unroll
        for (int kp = 0; kp < 4; ++kp) {
            int off = (q * 32 + kp * 8 + 8 * m16) & 127;
            f16x8 aw = *(const f16x8*)(lw + off);
            f16x4 alo = (f16x4){aw[0], aw[1], aw[2], aw[3]};
            f16x4 ahi = (f16x4){aw[4], aw[5], aw[6], aw[7]};
            aV  = mfma16(alo, Nv [2*kp], aV );
            aD  = mfma16(alo, Nd [2*kp], aD );
            aDD = mfma16(alo, Ndd[2*kp], aDD);
            aV  = mfma16(ahi, Nv [2*kp+1], aV );
            aD  = mfma16(ahi, Nd [2*kp+1], aD );
            aDD = mfma16(ahi, Ndd[2*kp+1], aDD);
        }
        const int h0 = 16 * mt + 4 * q;
        float4 bias = *(const float4*)(ldsB3 + h0);
        uint2 w4u = *(const uint2*)(w4t + n * HIDDEN + h0);   // f16 W4T[n][h0..h0+3]
        __half2 w4lo = u2h(w4u.x), w4hi = u2h(w4u.y);
        __half2 a0, ad0, add0, a1, ad1, add1;
        tanh_chain_h2(__floats2half2_rn(aV[0] + bias.x, aV[1] + bias.y),
                      __floats2half2_rn(aD[0], aD[1]),
                      __floats2half2_rn(aDD[0], aDD[1]), a0, ad0, add0);
        tanh_chain_h2(__floats2half2_rn(aV[2] + bias.z, aV[3] + bias.w),
                      __floats2half2_rn(aD[2], aD[3]),
                      __floats2half2_rn(aDD[2], aDD[3]), a1, ad1, add1);
        accV  = __hfma2(a0,  w4lo, accV );  accV  = __hfma2(a1,  w4hi, accV );
        accD  = __hfma2(ad0, w4lo, accD );  accD  = __hfma2(ad1, w4hi, accD );
        accDD = __hfma2(add0, w4lo, accDD); accDD = __hfma2(add1, w4hi, accDD);
    }
    float sv  = __low2float(accV)  + __high2float(accV);
    float sd  = __low2float(accD)  + __high2float(accD);
    float sdd = __low2float(accDD) + __high2float(accDD);

    // ---- reduce across the 4 quads of each eval ----
    sd  += __shfl_xor(sd,  16, 64);  sd  += __shfl_xor(sd,  32, 64);
    sdd += __shfl_xor(sdd, 16, 64);  sdd += __shfl_xor(sdd, 32, 64);
    sv  += __shfl_xor(sv,  16, 64);  sv  += __shfl_xor(sv,  32, 64);

    float contrib = -(sd * dB + sdd * dt * 0.5f);
    if (j == 0) contrib += sv + b4[n];

    // sum the wave's 16 evals (each 16-lane group holds a duplicate set)
    contrib += __shfl_xor(contrib, 1, 64);
    contrib += __shfl_xor(contrib, 2, 64);
    contrib += __shfl_xor(contrib, 4, 64);
    contrib += __shfl_xor(contrib, 8, 64);
    if (lane == 0) atomicAdd(&out[b], contrib);
}

extern "C" void kernel_launch(void* const* d_in, const int* in_sizes, int n_in,
                              void* d_out, int out_size, void* d_ws, size_t ws_size,
                              hipStream_t stream) {
    const float* W1 = (const float*)d_in[0];
    const float* b1 = (const float*)d_in[1];
    const float* W2 = (const float*)d_in[2];
    const float* b2 = (const float*)d_in[3];
    const float* W3 = (const float*)d_in[4];
    const float* b3 = (const float*)d_in[5];
    const float* W4 = (const float*)d_in[6];
    const float* b4 = (const float*)d_in[7];
    const int*   sn  = (const int*)d_in[8];
    const float* ss  = (const float*)d_in[9];
    const float* sdB = (const float*)d_in[10];
    const float* t   = (const float*)d_in[11];
    float* out = (float*)d_out;
    __half* wbf = (__half*)d_ws;   // 90 KB: W2^T, W3^T, W4^T in f16

    setup_kernel<<<(2 * HIDDEN * HIDDEN) / 256, 256, 0, stream>>>(W2, W3, W4, ss, wbf, out);
    eval_kernel<<<BATCH2, 256, 0, stream>>>(
        W1, b1, b2, b3, b4, wbf, sn, ss, sdB, t, out);
}

// Round 10
// 160.448 us; speedup vs baseline: 1.7199x; 1.0309x over previous
//
#include <hip/hip_runtime.h>
#include <hip/hip_fp16.h>
#include <math.h>

#define HIDDEN 128
#define NSTEP  64
#define BATCH2 4096
#define OUTD   100

typedef __attribute__((ext_vector_type(4))) _Float16 f16x4;
typedef __attribute__((ext_vector_type(8))) _Float16 f16x8;
typedef __attribute__((ext_vector_type(4))) float    f32x4;

static __device__ __forceinline__ f32x4 mfma16(f16x4 a, f16x4 b, f32x4 c) {
    return __builtin_amdgcn_mfma_f32_16x16x16f16(a, b, c, 0, 0, 0);
}
static __device__ __forceinline__ unsigned h2u(__half2 h) {
    return __builtin_bit_cast(unsigned, h);
}
static __device__ __forceinline__ __half2 u2h(unsigned u) {
    return __builtin_bit_cast(__half2, u);
}
static __device__ __forceinline__ f16x4 frag2(__half2 lo, __half2 hi) {
    uint2 p = { h2u(lo), h2u(hi) };
    return __builtin_bit_cast(f16x4, p);
}

// direct global->LDS DMA: lane i's 16B lands at ldsbase + 16*i
static __device__ __forceinline__ void load_lds16(const void* g, void* l) {
    __builtin_amdgcn_global_load_lds(
        (const __attribute__((address_space(1))) void*)g,
        (__attribute__((address_space(3))) void*)l, 16, 0, 0);
}

// packed-f16 tanh value+1st+2nd tangent chain (2 units per call)
// w = 2/(1+e^{2z}); a = 1-w; g = w(2-w); ad = g zd; add = g zdd - 2 a zd ad
static __device__ __forceinline__ void tanh_chain_h2(
    __half2 z, __half2 zd, __half2 zdd,
    __half2& a, __half2& ad, __half2& add)
{
    const __half2 one = __float2half2_rn(1.0f);
    const __half2 two = __float2half2_rn(2.0f);
    __half2 e = h2exp(__hadd2(z, z));
    __half2 w = __hmul2(two, h2rcp(__hadd2(e, one)));
    a  = __hsub2(one, w);
    __half2 g = __hmul2(w, __hsub2(two, w));
    ad = __hmul2(g, zd);
    __half2 p = __hmul2(a, zd);
    __half2 u = __hadd2(p, p);
    add = __hsub2(__hmul2(g, zdd), __hmul2(u, ad));
}

// d_ws layout (halfs):
//   [0..16383]      linear MFMA image of W2^T  (chunk(mt,kp): 64 lanes x 8 halfs)
//   [16384..32767]  linear MFMA image of W3^T
//   [32768..45567]  W4T[100][128]
// image[(4mt+kp)*512 + lane*8 + i] = W[k][16mt + (lane&15)],
//   k = 32kp + 16*(i>>2) + 4*(lane>>4) + (i&3)
__global__ __launch_bounds__(256) void setup_kernel(
    const float* __restrict__ W2, const float* __restrict__ W3,
    const float* __restrict__ W4,
    const float* __restrict__ samples_s,
    __half* __restrict__ wbf, float* __restrict__ out)
{
    int t = blockIdx.x * blockDim.x + threadIdx.x;   // 0..32767
    int l   = t >> 14;
    int pos = t & 16383;
    int chunk = pos >> 9;            // 0..31
    int mt = chunk >> 2, kp = chunk & 3;
    int lane = (pos >> 3) & 63;
    int i = pos & 7;
    int row = 16 * mt + (lane & 15);
    int k   = 32 * kp + 16 * (i >> 2) + 4 * (lane >> 4) + (i & 3);
    const float* W = l ? W3 : W2;
    wbf[t] = __float2half(W[k * HIDDEN + row]);
    if (t < OUTD * HIDDEN) {                         // W4T[n][h] = W4[h][n]
        int nn = t >> 7, h = t & 127;
        wbf[32768 + t] = __float2half(W4[h * OUTD + nn]);
    }
    if (t < BATCH2) {
        out[t] = 0.0f;
        float s0 = samples_s[t * (NSTEP + 1)];
        out[BATCH2 + t] = 3.9894228040143267f * expf(-500000.0f * s0 * s0);
    }
}

// One block = one sample = 64 evals. Wave w owns evals j = 16w + (lane&15);
// quad q holds k-slice {16kt + 4q + i}. Activations stay in registers as
// packed f16 (K16 C-frag == next layer's B-frag). Weights staged one layer
// at a time via global_load_lds from a pre-permuted linear image: zero
// address math, zero ds_write, conflict-free lane-ordered b128 reads.
__global__ __launch_bounds__(256, 3) void eval_kernel(
    const float* __restrict__ W1, const float* __restrict__ b1,
    const float* __restrict__ b2, const float* __restrict__ b3,
    const float* __restrict__ b4,
    const __half* __restrict__ wbf,
    const int*   __restrict__ samples_n,
    const float* __restrict__ samples_s,
    const float* __restrict__ samples_dB,
    const float* __restrict__ tptr,
    float* __restrict__ out)
{
    __shared__ __align__(16) short ldsW[HIDDEN * HIDDEN];  // 32 KB, one layer image
    __shared__ float ldsB2[HIDDEN];
    __shared__ float ldsB3[HIDDEN];

    const int tid  = threadIdx.x;
    const int w    = tid >> 6;
    const int lane = tid & 63;
    const int m16  = lane & 15;
    const int q    = lane >> 4;
    const int b    = blockIdx.x;

    // ---- stage layer-2 image (wave w: 1-KB chunks 8w..8w+7) + biases ----
    if (tid < HIDDEN) {
        ldsB2[tid] = b2[tid];
        ldsB3[tid] = b3[tid];
    }
    {
        const short* g2 = (const short*)wbf;
        #pragma unroll
        for (int it = 0; it < 8; ++it) {
            int idx = w * 8 + it;
            load_lds16(g2 + idx * 512 + lane * 8, ldsW + idx * 512);
        }
    }

    // per-eval scalars
    const float t  = tptr[0];
    const float dt = t / (float)NSTEP;
    const int   j  = 16 * w + m16;
    const int   c  = NSTEP - j;
    const float s  = samples_s[b * (NSTEP + 1) + c];
    const int   n  = samples_n[b * (NSTEP + 1) + c];
    const float dB = samples_dB[b * NSTEP + (NSTEP - 1 - j)];
    const float tk = (j == 0) ? t : t - dt * (float)(j - 1);

    // ---- layer 1: build packed-f16 B-fragments (h = 16kt + 4q + i) ----
    f16x4 Bv[8], Bd[8], Bdd[8];
    const __half2 zero2 = __float2half2_rn(0.0f);
    #pragma unroll
    for (int kt = 0; kt < 8; ++kt) {
        const int h0 = 16 * kt + 4 * q;
        float4 wa = *(const float4*)(W1 + h0);
        float4 wb = *(const float4*)(W1 + HIDDEN + h0);
        float4 bb = *(const float4*)(b1 + h0);
        __half2 z0 = __floats2half2_rn(fmaf(wa.x, s, fmaf(wb.x, tk, bb.x)),
                                       fmaf(wa.y, s, fmaf(wb.y, tk, bb.y)));
        __half2 z1 = __floats2half2_rn(fmaf(wa.z, s, fmaf(wb.z, tk, bb.z)),
                                       fmaf(wa.w, s, fmaf(wb.w, tk, bb.w)));
        __half2 zd0 = __floats2half2_rn(wa.x, wa.y);
        __half2 zd1 = __floats2half2_rn(wa.z, wa.w);
        __half2 a0, ad0, add0, a1, ad1, add1;
        tanh_chain_h2(z0, zd0, zero2, a0, ad0, add0);
        tanh_chain_h2(z1, zd1, zero2, a1, ad1, add1);
        Bv[kt]  = frag2(a0,  a1);
        Bd[kt]  = frag2(ad0, ad1);
        Bdd[kt] = frag2(add0, add1);
    }

    __syncthreads();   // layer-2 image + biases visible (drains vmcnt)

    // ---- layer 2: MFMA + packed-f16 epilogue -> next B-frags ----
    f16x4 Nv[8], Nd[8], Ndd[8];
    #pragma unroll
    for (int mt = 0; mt < 8; ++mt) {
        f32x4 aV = {0.f,0.f,0.f,0.f}, aD = {0.f,0.f,0.f,0.f}, aDD = {0.f,0.f,0.f,0.f};
        #pragma unroll
        for (int kp = 0; kp < 4; ++kp) {
            f16x8 aw = *(const f16x8*)(ldsW + ((mt * 4 + kp) << 9) + (lane << 3));
            f16x4 alo = (f16x4){aw[0], aw[1], aw[2], aw[3]};
            f16x4 ahi = (f16x4){aw[4], aw[5], aw[6], aw[7]};
            aV  = mfma16(alo, Bv [2*kp], aV );
            aD  = mfma16(alo, Bd [2*kp], aD );
            aDD = mfma16(alo, Bdd[2*kp], aDD);
            aV  = mfma16(ahi, Bv [2*kp+1], aV );
            aD  = mfma16(ahi, Bd [2*kp+1], aD );
            aDD = mfma16(ahi, Bdd[2*kp+1], aDD);
        }
        const int h0 = 16 * mt + 4 * q;            // C: h = h0 + r
        float4 bias = *(const float4*)(ldsB2 + h0);
        __half2 a0, ad0, add0, a1, ad1, add1;
        tanh_chain_h2(__floats2half2_rn(aV[0] + bias.x, aV[1] + bias.y),
                      __floats2half2_rn(aD[0], aD[1]),
                      __floats2half2_rn(aDD[0], aDD[1]), a0, ad0, add0);
        tanh_chain_h2(__floats2half2_rn(aV[2] + bias.z, aV[3] + bias.w),
                      __floats2half2_rn(aD[2], aD[3]),
                      __floats2half2_rn(aDD[2], aDD[3]), a1, ad1, add1);
        Nv[mt]  = frag2(a0,  a1);                  // == B-frag kt=mt of layer 3
        Nd[mt]  = frag2(ad0, ad1);
        Ndd[mt] = frag2(add0, add1);
    }

    __syncthreads();   // layer-2 weight reads done

    // ---- stage layer-3 image ----
    {
        const short* g3 = (const short*)(wbf + HIDDEN * HIDDEN);
        #pragma unroll
        for (int it = 0; it < 8; ++it) {
            int idx = w * 8 + it;
            load_lds16(g3 + idx * 512 + lane * 8, ldsW + idx * 512);
        }
    }
    __syncthreads();   // layer-3 image visible

    // ---- layer 3 + fused layer 4 (packed-f16 dot) ----
    const __half* __restrict__ w4t = wbf + 2 * HIDDEN * HIDDEN;
    __half2 accV = zero2, accD = zero2, accDD = zero2;
    #pragma unroll
    for (int mt = 0; mt < 8; ++mt) {
        f32x4 aV = {0.f,0.f,0.f,0.f}, aD = {0.f,0.f,0.f,0.f}, aDD = {0.f,0.f,0.f,0.f};
        #pragma unroll
        for (int kp = 0; kp < 4; ++kp) {
            f16x8 aw = *(const f16x8*)(ldsW + ((mt * 4 + kp) << 9) + (lane << 3));
            f16x4 alo = (f16x4){aw[0], aw[1], aw[2], aw[3]};
            f16x4 ahi = (f16x4){aw[4], aw[5], aw[6], aw[7]};
            aV  = mfma16(alo, Nv [2*kp], aV );
            aD  = mfma16(alo, Nd [2*kp], aD );
            aDD = mfma16(alo, Ndd[2*kp], aDD);
            aV  = mfma16(ahi, Nv [2*kp+1], aV );
            aD  = mfma16(ahi, Nd [2*kp+1], aD );
            aDD = mfma16(ahi, Ndd[2*kp+1], aDD);
        }
        const int h0 = 16 * mt + 4 * q;
        float4 bias = *(const float4*)(ldsB3 + h0);
        uint2 w4u = *(const uint2*)(w4t + n * HIDDEN + h0);   // f16 W4T[n][h0..h0+3]
        __half2 w4lo = u2h(w4u.x), w4hi = u2h(w4u.y);
        __half2 a0, ad0, add0, a1, ad1, add1;
        tanh_chain_h2(__floats2half2_rn(aV[0] + bias.x, aV[1] + bias.y),
                      __floats2half2_rn(aD[0], aD[1]),
                      __floats2half2_rn(aDD[0], aDD[1]), a0, ad0, add0);
        tanh_chain_h2(__floats2half2_rn(aV[2] + bias.z, aV[3] + bias.w),
                      __floats2half2_rn(aD[2], aD[3]),
                      __floats2half2_rn(aDD[2], aDD[3]), a1, ad1, add1);
        accV  = __hfma2(a0,  w4lo, accV );  accV  = __hfma2(a1,  w4hi, accV );
        accD  = __hfma2(ad0, w4lo, accD );  accD  = __hfma2(ad1, w4hi, accD );
        accDD = __hfma2(add0, w4lo, accDD); accDD = __hfma2(add1, w4hi, accDD);
    }
    float sv  = __low2float(accV)  + __high2float(accV);
    float sd  = __low2float(accD)  + __high2float(accD);
    float sdd = __low2float(accDD) + __high2float(accDD);

    // ---- reduce across the 4 quads of each eval ----
    sd  += __shfl_xor(sd,  16, 64);  sd  += __shfl_xor(sd,  32, 64);
    sdd += __shfl_xor(sdd, 16, 64);  sdd += __shfl_xor(sdd, 32, 64);
    sv  += __shfl_xor(sv,  16, 64);  sv  += __shfl_xor(sv,  32, 64);

    float contrib = -(sd * dB + sdd * dt * 0.5f);
    if (j == 0) contrib += sv + b4[n];

    // sum the wave's 16 evals (each 16-lane group holds a duplicate set)
    contrib += __shfl_xor(contrib, 1, 64);
    contrib += __shfl_xor(contrib, 2, 64);
    contrib += __shfl_xor(contrib, 4, 64);
    contrib += __shfl_xor(contrib, 8, 64);
    if (lane == 0) atomicAdd(&out[b], contrib);
}

extern "C" void kernel_launch(void* const* d_in, const int* in_sizes, int n_in,
                              void* d_out, int out_size, void* d_ws, size_t ws_size,
                              hipStream_t stream) {
    const float* W1 = (const float*)d_in[0];
    const float* b1 = (const float*)d_in[1];
    const float* W2 = (const float*)d_in[2];
    const float* b2 = (const float*)d_in[3];
    const float* W3 = (const float*)d_in[4];
    const float* b3 = (const float*)d_in[5];
    const float* W4 = (const float*)d_in[6];
    const float* b4 = (const float*)d_in[7];
    const int*   sn  = (const int*)d_in[8];
    const float* ss  = (const float*)d_in[9];
    const float* sdB = (const float*)d_in[10];
    const float* t   = (const float*)d_in[11];
    float* out = (float*)d_out;
    __half* wbf = (__half*)d_ws;   // 90 KB: W2/W3 MFMA images + W4^T (f16)

    setup_kernel<<<(2 * HIDDEN * HIDDEN) / 256, 256, 0, stream>>>(W2, W3, W4, ss, wbf, out);
    eval_kernel<<<BATCH2, 256, 0, stream>>>(
        W1, b1, b2, b3, b4, wbf, sn, ss, sdB, t, out);
}